// Round 2
// baseline (745.777 us; speedup 1.0000x reference)
//
#include <hip/hip_runtime.h>

// ---------------- CSR build ----------------

__global__ void zero_ints(int* __restrict__ p, int n) {
    int i = blockIdx.x * blockDim.x + threadIdx.x;
    if (i < n) p[i] = 0;
}

__global__ void count_kernel(const int* __restrict__ ei, int E,
                             int* __restrict__ cnt, int n) {
    int e = blockIdx.x * blockDim.x + threadIdx.x;
    if (e < E) {
        int d = ei[E + e];  // dst row of edge_index (int32 per harness contract)
        if ((unsigned)d < (unsigned)n) atomicAdd(&cnt[d], 1);
    }
}

// Single-block exclusive scan over n counts -> rowptr[0..n]; also dinv = rsqrt(cnt+1).
__global__ __launch_bounds__(1024) void scan_kernel(const int* __restrict__ cnt,
                                                    int* __restrict__ rowptr,
                                                    float* __restrict__ dinv, int n) {
    __shared__ int sums[1024];
    int t = threadIdx.x;
    int chunk = (n + 1023) >> 10;
    int beg = t * chunk;
    int end = beg + chunk;
    if (beg > n) beg = n;
    if (end > n) end = n;
    int s = 0;
    for (int i = beg; i < end; ++i) s += cnt[i];
    sums[t] = s;
    __syncthreads();
    for (int off = 1; off < 1024; off <<= 1) {
        int v = (t >= off) ? sums[t - off] : 0;
        __syncthreads();
        sums[t] += v;
        __syncthreads();
    }
    int run = (t == 0) ? 0 : sums[t - 1];
    for (int i = beg; i < end; ++i) {
        rowptr[i] = run;
        run += cnt[i];
        dinv[i] = rsqrtf((float)(cnt[i] + 1));  // +1 self-loop
    }
    if (t == 1023) rowptr[n] = sums[1023];
}

__global__ void fill_kernel(const int* __restrict__ ei, int E,
                            const int* __restrict__ rowptr,
                            int* __restrict__ fill, int* __restrict__ srcs, int n) {
    int e = blockIdx.x * blockDim.x + threadIdx.x;
    if (e < E) {
        int s = ei[e];
        int d = ei[E + e];
        if ((unsigned)d < (unsigned)n && (unsigned)s < (unsigned)n) {
            int pos = rowptr[d] + atomicAdd(&fill[d], 1);
            srcs[pos] = s;
        }
    }
}

// ---------------- GEMM with dinv row-scaling epilogue ----------------
// G[r][c] = (sum_k X[r][k] * W[k][c]) * dinv[r].  K = 128 fixed.
// W read straight from global (L1/L2-resident, <=64 KB); only X staged in LDS.

template <int M>
__global__ __launch_bounds__(256) void gemm_scale(const float* __restrict__ X,
                                                  const float* __restrict__ W,
                                                  const float* __restrict__ dinv,
                                                  float* __restrict__ G, int n) {
    constexpr int K = 128;
    constexpr int ROWS = 32;
    __shared__ float Xs[ROWS * K];  // 16 KB
    int t = threadIdx.x;
    int block_row = blockIdx.x * ROWS;

    {
        const float4* X4 = (const float4*)(X + (size_t)block_row * K);
        float4* Xs4 = (float4*)Xs;
        for (int i = t; i < ROWS * K / 4; i += 256) Xs4[i] = X4[i];
    }
    __syncthreads();

    constexpr int NCG = M / 4;     // float4 col-groups
    constexpr int RG = 256 / NCG;  // row groups
    constexpr int RPT = ROWS / RG; // rows per thread
    int cg = t % NCG;
    int rg = t / NCG;

    float4 acc[RPT];
#pragma unroll
    for (int j = 0; j < RPT; ++j) acc[j] = make_float4(0.f, 0.f, 0.f, 0.f);

    const float4* W4 = (const float4*)W;
#pragma unroll 4
    for (int k = 0; k < K; ++k) {
        float4 w = W4[k * NCG + cg];
#pragma unroll
        for (int j = 0; j < RPT; ++j) {
            float xv = Xs[(rg + j * RG) * K + k];
            acc[j].x += xv * w.x;
            acc[j].y += xv * w.y;
            acc[j].z += xv * w.z;
            acc[j].w += xv * w.w;
        }
    }

#pragma unroll
    for (int j = 0; j < RPT; ++j) {
        int r = block_row + rg + j * RG;
        if (r < n) {
            float di = dinv[r];
            ((float4*)(G + (size_t)r * M))[cg] =
                make_float4(acc[j].x * di, acc[j].y * di, acc[j].z * di, acc[j].w * di);
        }
    }
}

// ---------------- Aggregation: out[i] = (sum_{s in N(i)} g[s] + g[i]) * dinv[i] + b ----------------

__global__ __launch_bounds__(256) void agg_d128(const float* __restrict__ G,
                                                const int* __restrict__ srcs,
                                                const int* __restrict__ rowptr,
                                                const float* __restrict__ dinv,
                                                const float* __restrict__ bias,
                                                float* __restrict__ out, int n,
                                                int do_relu) {
    int wid = (blockIdx.x * blockDim.x + threadIdx.x) >> 6;
    int lane = threadIdx.x & 63;
    if (wid >= n) return;

    float2 acc = ((const float2*)(G + (size_t)wid * 128))[lane];  // self-loop
    int beg = rowptr[wid], end = rowptr[wid + 1];
    for (int base = beg; base < end; base += 64) {
        int m = end - base;
        if (m > 64) m = 64;
        int sv = (base + lane < end) ? srcs[base + lane] : 0;
        for (int j = 0; j < m; ++j) {
            int s = __shfl(sv, j);
            float2 v = ((const float2*)(G + (size_t)s * 128))[lane];
            acc.x += v.x;
            acc.y += v.y;
        }
    }
    float di = dinv[wid];
    float2 b = ((const float2*)bias)[lane];
    float ox = acc.x * di + b.x;
    float oy = acc.y * di + b.y;
    if (do_relu) {
        ox = fmaxf(ox, 0.f);
        oy = fmaxf(oy, 0.f);
    }
    ((float2*)(out + (size_t)wid * 128))[lane] = make_float2(ox, oy);
}

__global__ __launch_bounds__(256) void agg_d64(const float* __restrict__ G,
                                               const int* __restrict__ srcs,
                                               const int* __restrict__ rowptr,
                                               const float* __restrict__ dinv,
                                               const float* __restrict__ bias,
                                               float* __restrict__ out, int n) {
    int wid = (blockIdx.x * blockDim.x + threadIdx.x) >> 6;
    int lane = threadIdx.x & 63;
    if (wid >= n) return;

    float acc = G[(size_t)wid * 64 + lane];  // self-loop
    int beg = rowptr[wid], end = rowptr[wid + 1];
    for (int base = beg; base < end; base += 64) {
        int m = end - base;
        if (m > 64) m = 64;
        int sv = (base + lane < end) ? srcs[base + lane] : 0;
        for (int j = 0; j < m; ++j) {
            int s = __shfl(sv, j);
            acc += G[(size_t)s * 64 + lane];
        }
    }
    out[(size_t)wid * 64 + lane] = acc * dinv[wid] + bias[lane];
}

// ---------------- launch ----------------

extern "C" void kernel_launch(void* const* d_in, const int* in_sizes, int n_in,
                              void* d_out, int out_size, void* d_ws, size_t ws_size,
                              hipStream_t stream) {
    const float* x = (const float*)d_in[0];
    const int* ei = (const int*)d_in[1];  // int32 per harness contract
    const float* W1 = (const float*)d_in[2];
    const float* b1 = (const float*)d_in[3];
    const float* W2 = (const float*)d_in[4];
    const float* b2 = (const float*)d_in[5];
    float* out = (float*)d_out;

    const int n = in_sizes[0] / 128;  // 100000
    const int E = in_sizes[1] / 2;    // 1600000

    char* ws = (char*)d_ws;
    size_t off = 0;
    auto alloc = [&](size_t bytes) {
        void* p = ws + off;
        off = (off + bytes + 255) & ~(size_t)255;
        return p;
    };
    float* g1 = (float*)alloc((size_t)n * 128 * 4);  // scaled hidden, reused as g2
    float* a1 = (float*)alloc((size_t)n * 128 * 4);  // relu(layer1 out)
    int* cnt = (int*)alloc((size_t)n * 4);
    int* fill = (int*)alloc((size_t)n * 4);
    int* rowptr = (int*)alloc(((size_t)n + 1) * 4);
    float* dinv = (float*)alloc((size_t)n * 4);
    int* srcs = (int*)alloc((size_t)E * 4);
    float* g2 = g1;

    int nb = (n + 255) / 256;
    int eb = (E + 255) / 256;

    zero_ints<<<nb, 256, 0, stream>>>(cnt, n);
    zero_ints<<<nb, 256, 0, stream>>>(fill, n);
    count_kernel<<<eb, 256, 0, stream>>>(ei, E, cnt, n);
    scan_kernel<<<1, 1024, 0, stream>>>(cnt, rowptr, dinv, n);
    fill_kernel<<<eb, 256, 0, stream>>>(ei, E, rowptr, fill, srcs, n);

    // layer 1
    gemm_scale<128><<<(n + 31) / 32, 256, 0, stream>>>(x, W1, dinv, g1, n);
    agg_d128<<<(n + 3) / 4, 256, 0, stream>>>(g1, srcs, rowptr, dinv, b1, a1, n, 1);

    // layer 2
    gemm_scale<64><<<(n + 31) / 32, 256, 0, stream>>>(a1, W2, dinv, g2, n);
    agg_d64<<<(n + 3) / 4, 256, 0, stream>>>(g2, srcs, rowptr, dinv, b2, out, n);
}

// Round 3
// 529.423 us; speedup vs baseline: 1.4087x; 1.4087x over previous
//
#include <hip/hip_runtime.h>

// ---------------- CSR build ----------------

__global__ void count_kernel(const int* __restrict__ ei, int E,
                             int* __restrict__ cnt, int n) {
    int e = blockIdx.x * blockDim.x + threadIdx.x;
    if (e < E) {
        int d = ei[E + e];  // dst row of edge_index (int32 per harness contract)
        if ((unsigned)d < (unsigned)n) atomicAdd(&cnt[d], 1);
    }
}

// ---- 3-phase parallel exclusive scan over cnt[0..n) -> rowptr[0..n], dinv ----
// Phase 1: each block sums a 1024-element chunk.
__global__ __launch_bounds__(256) void scan_partial(const int* __restrict__ cnt,
                                                    int n, int* __restrict__ blocksum) {
    int base = blockIdx.x * 1024;
    int t = threadIdx.x;
    int s = 0;
#pragma unroll
    for (int j = 0; j < 4; ++j) {
        int i = base + (t << 2) + j;
        if (i < n) s += cnt[i];
    }
#pragma unroll
    for (int off = 1; off < 64; off <<= 1) s += __shfl_xor(s, off);
    __shared__ int ws[4];
    if ((t & 63) == 0) ws[t >> 6] = s;
    __syncthreads();
    if (t == 0) blocksum[blockIdx.x] = ws[0] + ws[1] + ws[2] + ws[3];
}

// Phase 2: single small block turns blocksum into exclusive block offsets (nb <= 256).
__global__ __launch_bounds__(256) void scan_blocksums(int* __restrict__ blocksum, int nb) {
    __shared__ int sh[256];
    int t = threadIdx.x;
    sh[t] = (t < nb) ? blocksum[t] : 0;
    __syncthreads();
#pragma unroll
    for (int off = 1; off < 256; off <<= 1) {
        int v = (t >= off) ? sh[t - off] : 0;
        __syncthreads();
        sh[t] += v;
        __syncthreads();
    }
    if (t < nb) blocksum[t] = (t == 0) ? 0 : sh[t - 1];
}

// Phase 3: local exclusive scan within each chunk + block offset; writes rowptr & dinv.
__global__ __launch_bounds__(256) void scan_final(const int* __restrict__ cnt,
                                                  const int* __restrict__ blockoff,
                                                  int n, int* __restrict__ rowptr,
                                                  float* __restrict__ dinv) {
    int base = blockIdx.x * 1024;
    int t = threadIdx.x;
    int v[4];
    int s = 0;
#pragma unroll
    for (int j = 0; j < 4; ++j) {
        int i = base + (t << 2) + j;
        v[j] = (i < n) ? cnt[i] : 0;
        s += v[j];
    }
    __shared__ int sh[256];
    sh[t] = s;
    __syncthreads();
#pragma unroll
    for (int off = 1; off < 256; off <<= 1) {
        int x = (t >= off) ? sh[t - off] : 0;
        __syncthreads();
        sh[t] += x;
        __syncthreads();
    }
    int run = blockoff[blockIdx.x] + (sh[t] - s);  // exclusive prefix for this thread
#pragma unroll
    for (int j = 0; j < 4; ++j) {
        int i = base + (t << 2) + j;
        if (i < n) {
            rowptr[i] = run;
            dinv[i] = rsqrtf((float)(v[j] + 1));  // +1 self-loop
            run += v[j];
        }
    }
    if (base + (t << 2) < n && n <= base + (t << 2) + 4) rowptr[n] = run;
}

__global__ void fill_kernel(const int* __restrict__ ei, int E,
                            const int* __restrict__ rowptr,
                            int* __restrict__ fill, int* __restrict__ srcs, int n) {
    int e = blockIdx.x * blockDim.x + threadIdx.x;
    if (e < E) {
        int s = ei[e];
        int d = ei[E + e];
        if ((unsigned)d < (unsigned)n && (unsigned)s < (unsigned)n) {
            int pos = rowptr[d] + atomicAdd(&fill[d], 1);
            srcs[pos] = s;
        }
    }
}

// ---------------- GEMM with dinv row-scaling epilogue ----------------
// G[r][c] = (sum_k X[r][k] * W[k][c]) * dinv[r].  K = 128 fixed.

template <int M>
__global__ __launch_bounds__(256) void gemm_scale(const float* __restrict__ X,
                                                  const float* __restrict__ W,
                                                  const float* __restrict__ dinv,
                                                  float* __restrict__ G, int n) {
    constexpr int K = 128;
    constexpr int ROWS = 32;
    __shared__ float Xs[ROWS * K];  // 16 KB
    int t = threadIdx.x;
    int block_row = blockIdx.x * ROWS;

    {
        const float4* X4 = (const float4*)(X + (size_t)block_row * K);
        float4* Xs4 = (float4*)Xs;
        for (int i = t; i < ROWS * K / 4; i += 256) Xs4[i] = X4[i];
    }
    __syncthreads();

    constexpr int NCG = M / 4;     // float4 col-groups
    constexpr int RG = 256 / NCG;  // row groups
    constexpr int RPT = ROWS / RG; // rows per thread
    int cg = t % NCG;
    int rg = t / NCG;

    float4 acc[RPT];
#pragma unroll
    for (int j = 0; j < RPT; ++j) acc[j] = make_float4(0.f, 0.f, 0.f, 0.f);

    const float4* W4 = (const float4*)W;
#pragma unroll 4
    for (int k = 0; k < K; ++k) {
        float4 w = W4[k * NCG + cg];
#pragma unroll
        for (int j = 0; j < RPT; ++j) {
            float xv = Xs[(rg + j * RG) * K + k];
            acc[j].x += xv * w.x;
            acc[j].y += xv * w.y;
            acc[j].z += xv * w.z;
            acc[j].w += xv * w.w;
        }
    }

#pragma unroll
    for (int j = 0; j < RPT; ++j) {
        int r = block_row + rg + j * RG;
        if (r < n) {
            float di = dinv[r];
            ((float4*)(G + (size_t)r * M))[cg] =
                make_float4(acc[j].x * di, acc[j].y * di, acc[j].z * di, acc[j].w * di);
        }
    }
}

// ---------------- Aggregation: out[i] = (sum_{s in N(i)} g[s] + g[i]) * dinv[i] + b ----------------

__global__ __launch_bounds__(256) void agg_d128(const float* __restrict__ G,
                                                const int* __restrict__ srcs,
                                                const int* __restrict__ rowptr,
                                                const float* __restrict__ dinv,
                                                const float* __restrict__ bias,
                                                float* __restrict__ out, int n,
                                                int do_relu) {
    int wid = (blockIdx.x * blockDim.x + threadIdx.x) >> 6;
    int lane = threadIdx.x & 63;
    if (wid >= n) return;

    float2 acc = ((const float2*)(G + (size_t)wid * 128))[lane];  // self-loop
    int beg = rowptr[wid], end = rowptr[wid + 1];
    for (int base = beg; base < end; base += 64) {
        int m = end - base;
        if (m > 64) m = 64;
        int sv = (base + lane < end) ? srcs[base + lane] : 0;
        for (int j = 0; j < m; ++j) {
            int s = __shfl(sv, j);
            float2 v = ((const float2*)(G + (size_t)s * 128))[lane];
            acc.x += v.x;
            acc.y += v.y;
        }
    }
    float di = dinv[wid];
    float2 b = ((const float2*)bias)[lane];
    float ox = acc.x * di + b.x;
    float oy = acc.y * di + b.y;
    if (do_relu) {
        ox = fmaxf(ox, 0.f);
        oy = fmaxf(oy, 0.f);
    }
    ((float2*)(out + (size_t)wid * 128))[lane] = make_float2(ox, oy);
}

__global__ __launch_bounds__(256) void agg_d64(const float* __restrict__ G,
                                               const int* __restrict__ srcs,
                                               const int* __restrict__ rowptr,
                                               const float* __restrict__ dinv,
                                               const float* __restrict__ bias,
                                               float* __restrict__ out, int n) {
    int wid = (blockIdx.x * blockDim.x + threadIdx.x) >> 6;
    int lane = threadIdx.x & 63;
    if (wid >= n) return;

    float acc = G[(size_t)wid * 64 + lane];  // self-loop
    int beg = rowptr[wid], end = rowptr[wid + 1];
    for (int base = beg; base < end; base += 64) {
        int m = end - base;
        if (m > 64) m = 64;
        int sv = (base + lane < end) ? srcs[base + lane] : 0;
        for (int j = 0; j < m; ++j) {
            int s = __shfl(sv, j);
            acc += G[(size_t)s * 64 + lane];
        }
    }
    out[(size_t)wid * 64 + lane] = acc * dinv[wid] + bias[lane];
}

// ---------------- launch ----------------

extern "C" void kernel_launch(void* const* d_in, const int* in_sizes, int n_in,
                              void* d_out, int out_size, void* d_ws, size_t ws_size,
                              hipStream_t stream) {
    const float* x = (const float*)d_in[0];
    const int* ei = (const int*)d_in[1];  // int32 per harness contract
    const float* W1 = (const float*)d_in[2];
    const float* b1 = (const float*)d_in[3];
    const float* W2 = (const float*)d_in[4];
    const float* b2 = (const float*)d_in[5];
    float* out = (float*)d_out;

    const int n = in_sizes[0] / 128;  // 100000
    const int E = in_sizes[1] / 2;    // 1600000

    char* ws = (char*)d_ws;
    size_t off = 0;
    auto alloc = [&](size_t bytes) {
        void* p = ws + off;
        off = (off + bytes + 255) & ~(size_t)255;
        return p;
    };
    float* g1 = (float*)alloc((size_t)n * 128 * 4);  // scaled hidden, reused as g2
    float* a1 = (float*)alloc((size_t)n * 128 * 4);  // relu(layer1 out)
    int* cnt = (int*)alloc((size_t)n * 4);
    int* fill = (int*)alloc((size_t)n * 4);
    int* rowptr = (int*)alloc(((size_t)n + 1) * 4);
    float* dinv = (float*)alloc((size_t)n * 4);
    int* srcs = (int*)alloc((size_t)E * 4);
    int* blocksum = (int*)alloc(1024 * 4);
    float* g2 = g1;

    const int nb_scan = (n + 1023) / 1024;  // 98 blocks, <=256 required
    int eb = (E + 255) / 256;

    // zero cnt..fill region in one async memset (contiguous by construction)
    size_t zbytes = (size_t)((char*)fill - (char*)cnt) + (size_t)n * 4;
    hipMemsetAsync(cnt, 0, zbytes, stream);

    count_kernel<<<eb, 256, 0, stream>>>(ei, E, cnt, n);
    scan_partial<<<nb_scan, 256, 0, stream>>>(cnt, n, blocksum);
    scan_blocksums<<<1, 256, 0, stream>>>(blocksum, nb_scan);
    scan_final<<<nb_scan, 256, 0, stream>>>(cnt, blocksum, n, rowptr, dinv);
    fill_kernel<<<eb, 256, 0, stream>>>(ei, E, rowptr, fill, srcs, n);

    // layer 1
    gemm_scale<128><<<(n + 31) / 32, 256, 0, stream>>>(x, W1, dinv, g1, n);
    agg_d128<<<(n + 3) / 4, 256, 0, stream>>>(g1, srcs, rowptr, dinv, b1, a1, n, 1);

    // layer 2
    gemm_scale<64><<<(n + 31) / 32, 256, 0, stream>>>(a1, W2, dinv, g2, n);
    agg_d64<<<(n + 3) / 4, 256, 0, stream>>>(g2, srcs, rowptr, dinv, b2, out, n);
}

// Round 4
// 502.203 us; speedup vs baseline: 1.4850x; 1.0542x over previous
//
#include <hip/hip_runtime.h>

// ---------------- bf16 helpers (hand-rolled RNE) ----------------

__device__ __forceinline__ unsigned short f2bf(float f) {
    unsigned u = __float_as_uint(f);
    u += 0x7fffu + ((u >> 16) & 1u);
    return (unsigned short)(u >> 16);
}
__device__ __forceinline__ float bf_lo(unsigned u) {  // low 16 bits -> float
    return __uint_as_float(u << 16);
}
__device__ __forceinline__ float bf_hi(unsigned u) {  // high 16 bits -> float
    return __uint_as_float(u & 0xffff0000u);
}

// ---------------- CSR build ----------------

__global__ void count_kernel(const int* __restrict__ ei, int E,
                             int* __restrict__ cnt, int n) {
    int e = blockIdx.x * blockDim.x + threadIdx.x;
    if (e < E) {
        int d = ei[E + e];  // dst row (int32 per harness contract)
        if ((unsigned)d < (unsigned)n) atomicAdd(&cnt[d], 1);
    }
}

// ---- 3-phase parallel exclusive scan over cnt[0..n) -> rowptr[0..n], dinv ----
__global__ __launch_bounds__(256) void scan_partial(const int* __restrict__ cnt,
                                                    int n, int* __restrict__ blocksum) {
    int base = blockIdx.x * 1024;
    int t = threadIdx.x;
    int s = 0;
#pragma unroll
    for (int j = 0; j < 4; ++j) {
        int i = base + (t << 2) + j;
        if (i < n) s += cnt[i];
    }
#pragma unroll
    for (int off = 1; off < 64; off <<= 1) s += __shfl_xor(s, off);
    __shared__ int ws[4];
    if ((t & 63) == 0) ws[t >> 6] = s;
    __syncthreads();
    if (t == 0) blocksum[blockIdx.x] = ws[0] + ws[1] + ws[2] + ws[3];
}

__global__ __launch_bounds__(256) void scan_blocksums(int* __restrict__ blocksum, int nb) {
    __shared__ int sh[256];
    int t = threadIdx.x;
    sh[t] = (t < nb) ? blocksum[t] : 0;
    __syncthreads();
#pragma unroll
    for (int off = 1; off < 256; off <<= 1) {
        int v = (t >= off) ? sh[t - off] : 0;
        __syncthreads();
        sh[t] += v;
        __syncthreads();
    }
    if (t < nb) blocksum[t] = (t == 0) ? 0 : sh[t - 1];
}

__global__ __launch_bounds__(256) void scan_final(const int* __restrict__ cnt,
                                                  const int* __restrict__ blockoff,
                                                  int n, int* __restrict__ rowptr,
                                                  float* __restrict__ dinv) {
    int base = blockIdx.x * 1024;
    int t = threadIdx.x;
    int v[4];
    int s = 0;
#pragma unroll
    for (int j = 0; j < 4; ++j) {
        int i = base + (t << 2) + j;
        v[j] = (i < n) ? cnt[i] : 0;
        s += v[j];
    }
    __shared__ int sh[256];
    sh[t] = s;
    __syncthreads();
#pragma unroll
    for (int off = 1; off < 256; off <<= 1) {
        int x = (t >= off) ? sh[t - off] : 0;
        __syncthreads();
        sh[t] += x;
        __syncthreads();
    }
    int run = blockoff[blockIdx.x] + (sh[t] - s);
#pragma unroll
    for (int j = 0; j < 4; ++j) {
        int i = base + (t << 2) + j;
        if (i < n) {
            rowptr[i] = run;
            dinv[i] = rsqrtf((float)(v[j] + 1));  // +1 self-loop
            run += v[j];
        }
    }
    if (base + (t << 2) < n && n <= base + (t << 2) + 4) rowptr[n] = run;
}

__global__ void fill_kernel(const int* __restrict__ ei, int E,
                            const int* __restrict__ rowptr,
                            int* __restrict__ fill, int* __restrict__ srcs, int n) {
    int e = blockIdx.x * blockDim.x + threadIdx.x;
    if (e < E) {
        int s = ei[e];
        int d = ei[E + e];
        if ((unsigned)d < (unsigned)n && (unsigned)s < (unsigned)n) {
            int pos = rowptr[d] + atomicAdd(&fill[d], 1);
            srcs[pos] = s;
        }
    }
}

// ---------------- GEMM: G16[r][c] = bf16( (X[r]·W[:,c]) * dinv[r] ) ----------------
// K = 128 fixed. W read from global (L2-resident), X tile staged in LDS.

template <int M>
__global__ __launch_bounds__(256) void gemm_scale_bf16(const float* __restrict__ X,
                                                       const float* __restrict__ W,
                                                       const float* __restrict__ dinv,
                                                       unsigned short* __restrict__ G16,
                                                       int n) {
    constexpr int K = 128;
    constexpr int ROWS = 32;
    __shared__ float Xs[ROWS * K];  // 16 KB
    int t = threadIdx.x;
    int block_row = blockIdx.x * ROWS;

    {
        const float4* X4 = (const float4*)(X + (size_t)block_row * K);
        float4* Xs4 = (float4*)Xs;
        for (int i = t; i < ROWS * K / 4; i += 256) Xs4[i] = X4[i];
    }
    __syncthreads();

    constexpr int NCG = M / 4;     // float4 col-groups
    constexpr int RG = 256 / NCG;  // row groups
    constexpr int RPT = ROWS / RG; // rows per thread
    int cg = t % NCG;
    int rg = t / NCG;

    float4 acc[RPT];
#pragma unroll
    for (int j = 0; j < RPT; ++j) acc[j] = make_float4(0.f, 0.f, 0.f, 0.f);

    const float4* W4 = (const float4*)W;
#pragma unroll 4
    for (int k = 0; k < K; ++k) {
        float4 w = W4[k * NCG + cg];
#pragma unroll
        for (int j = 0; j < RPT; ++j) {
            float xv = Xs[(rg + j * RG) * K + k];
            acc[j].x += xv * w.x;
            acc[j].y += xv * w.y;
            acc[j].z += xv * w.z;
            acc[j].w += xv * w.w;
        }
    }

#pragma unroll
    for (int j = 0; j < RPT; ++j) {
        int r = block_row + rg + j * RG;
        if (r < n) {
            float di = dinv[r];
            ushort4 v;
            v.x = f2bf(acc[j].x * di);
            v.y = f2bf(acc[j].y * di);
            v.z = f2bf(acc[j].z * di);
            v.w = f2bf(acc[j].w * di);
            ((ushort4*)(G16 + (size_t)r * M))[cg] = v;
        }
    }
}

// ---------------- Aggregation (bf16 table, fp32 accumulate) ----------------
// out[i] = (sum_{s in N(i)} g[s] + g[i]) * dinv[i] + b

__global__ __launch_bounds__(256) void agg_d128(const unsigned short* __restrict__ G16,
                                                const int* __restrict__ srcs,
                                                const int* __restrict__ rowptr,
                                                const float* __restrict__ dinv,
                                                const float* __restrict__ bias,
                                                float* __restrict__ out, int n,
                                                int do_relu) {
    int wid = (blockIdx.x * blockDim.x + threadIdx.x) >> 6;
    int lane = threadIdx.x & 63;
    if (wid >= n) return;

    // row = 128 bf16 = 64 dwords; lane's dword = cols (2*lane, 2*lane+1)
    const unsigned* rowp = (const unsigned*)(G16 + (size_t)wid * 128);
    unsigned u = rowp[lane];  // self-loop
    float accx = bf_lo(u), accy = bf_hi(u);

    int beg = rowptr[wid], end = rowptr[wid + 1];
    for (int base = beg; base < end; base += 64) {
        int m = end - base;
        if (m > 64) m = 64;
        int sv = (base + lane < end) ? srcs[base + lane] : 0;
        for (int j = 0; j < m; ++j) {
            int s = __shfl(sv, j);
            unsigned g = ((const unsigned*)(G16 + (size_t)s * 128))[lane];
            accx += bf_lo(g);
            accy += bf_hi(g);
        }
    }
    float di = dinv[wid];
    float2 b = ((const float2*)bias)[lane];
    float ox = accx * di + b.x;
    float oy = accy * di + b.y;
    if (do_relu) {
        ox = fmaxf(ox, 0.f);
        oy = fmaxf(oy, 0.f);
    }
    ((float2*)(out + (size_t)wid * 128))[lane] = make_float2(ox, oy);
}

__global__ __launch_bounds__(256) void agg_d64(const unsigned short* __restrict__ G16,
                                               const int* __restrict__ srcs,
                                               const int* __restrict__ rowptr,
                                               const float* __restrict__ dinv,
                                               const float* __restrict__ bias,
                                               float* __restrict__ out, int n) {
    int wid = (blockIdx.x * blockDim.x + threadIdx.x) >> 6;
    int lane = threadIdx.x & 63;
    if (wid >= n) return;

    // row = 64 bf16 = 128 B; lane reads one ushort (col = lane)
    float acc = __uint_as_float(((unsigned)G16[(size_t)wid * 64 + lane]) << 16);

    int beg = rowptr[wid], end = rowptr[wid + 1];
    for (int base = beg; base < end; base += 64) {
        int m = end - base;
        if (m > 64) m = 64;
        int sv = (base + lane < end) ? srcs[base + lane] : 0;
        for (int j = 0; j < m; ++j) {
            int s = __shfl(sv, j);
            acc += __uint_as_float(((unsigned)G16[(size_t)s * 64 + lane]) << 16);
        }
    }
    out[(size_t)wid * 64 + lane] = acc * dinv[wid] + bias[lane];
}

// ---------------- launch ----------------

extern "C" void kernel_launch(void* const* d_in, const int* in_sizes, int n_in,
                              void* d_out, int out_size, void* d_ws, size_t ws_size,
                              hipStream_t stream) {
    const float* x = (const float*)d_in[0];
    const int* ei = (const int*)d_in[1];
    const float* W1 = (const float*)d_in[2];
    const float* b1 = (const float*)d_in[3];
    const float* W2 = (const float*)d_in[4];
    const float* b2 = (const float*)d_in[5];
    float* out = (float*)d_out;

    const int n = in_sizes[0] / 128;  // 100000
    const int E = in_sizes[1] / 2;    // 1600000

    char* ws = (char*)d_ws;
    size_t off = 0;
    auto alloc = [&](size_t bytes) {
        void* p = ws + off;
        off = (off + bytes + 255) & ~(size_t)255;
        return p;
    };
    unsigned short* g1 = (unsigned short*)alloc((size_t)n * 128 * 2);  // bf16 gather table L1
    float* a1 = (float*)alloc((size_t)n * 128 * 4);                    // relu(layer1 out), fp32
    int* cnt = (int*)alloc((size_t)n * 4);
    int* fill = (int*)alloc((size_t)n * 4);
    int* rowptr = (int*)alloc(((size_t)n + 1) * 4);
    float* dinv = (float*)alloc((size_t)n * 4);
    int* srcs = (int*)alloc((size_t)E * 4);
    int* blocksum = (int*)alloc(1024 * 4);
    unsigned short* g2 = g1;  // bf16 gather table L2 (reuse; 12.8 MB <= 25.6 MB)

    const int nb_scan = (n + 1023) / 1024;  // 98 blocks, <=256 required
    int eb = (E + 255) / 256;

    // zero cnt..fill region in one async memset (contiguous by construction)
    size_t zbytes = (size_t)((char*)fill - (char*)cnt) + (size_t)n * 4;
    hipMemsetAsync(cnt, 0, zbytes, stream);

    count_kernel<<<eb, 256, 0, stream>>>(ei, E, cnt, n);
    scan_partial<<<nb_scan, 256, 0, stream>>>(cnt, n, blocksum);
    scan_blocksums<<<1, 256, 0, stream>>>(blocksum, nb_scan);
    scan_final<<<nb_scan, 256, 0, stream>>>(cnt, blocksum, n, rowptr, dinv);
    fill_kernel<<<eb, 256, 0, stream>>>(ei, E, rowptr, fill, srcs, n);

    // layer 1
    gemm_scale_bf16<128><<<(n + 31) / 32, 256, 0, stream>>>(x, W1, dinv, g1, n);
    agg_d128<<<(n + 3) / 4, 256, 0, stream>>>(g1, srcs, rowptr, dinv, b1, a1, n, 1);

    // layer 2
    gemm_scale_bf16<64><<<(n + 31) / 32, 256, 0, stream>>>(a1, W2, dinv, g2, n);
    agg_d64<<<(n + 3) / 4, 256, 0, stream>>>(g2, srcs, rowptr, dinv, b2, out, n);
}

// Round 5
// 429.324 us; speedup vs baseline: 1.7371x; 1.1698x over previous
//
#include <hip/hip_runtime.h>

// ---------------- bf16 helpers (hand-rolled RNE) ----------------

__device__ __forceinline__ unsigned short f2bf(float f) {
    unsigned u = __float_as_uint(f);
    u += 0x7fffu + ((u >> 16) & 1u);
    return (unsigned short)(u >> 16);
}
__device__ __forceinline__ float bf_lo(unsigned u) {  // low 16 bits -> float
    return __uint_as_float(u << 16);
}
__device__ __forceinline__ float bf_hi(unsigned u) {  // high 16 bits -> float
    return __uint_as_float(u & 0xffff0000u);
}

// ---------------- CSR build ----------------
// Pass 1: per-dst counts AND per-edge rank from the same atomic.
__global__ void count_rank(const int* __restrict__ ei, int E,
                           int* __restrict__ cnt, int* __restrict__ rank, int n) {
    int e = blockIdx.x * blockDim.x + threadIdx.x;
    if (e < E) {
        int d = ei[E + e];  // dst row (int32 per harness contract)
        if ((unsigned)d < (unsigned)n) rank[e] = atomicAdd(&cnt[d], 1);
    }
}

// ---- 3-phase parallel exclusive scan over cnt[0..n) -> rowptr[0..n], dinv ----
__global__ __launch_bounds__(256) void scan_partial(const int* __restrict__ cnt,
                                                    int n, int* __restrict__ blocksum) {
    int base = blockIdx.x * 1024;
    int t = threadIdx.x;
    int s = 0;
#pragma unroll
    for (int j = 0; j < 4; ++j) {
        int i = base + (t << 2) + j;
        if (i < n) s += cnt[i];
    }
#pragma unroll
    for (int off = 1; off < 64; off <<= 1) s += __shfl_xor(s, off);
    __shared__ int ws[4];
    if ((t & 63) == 0) ws[t >> 6] = s;
    __syncthreads();
    if (t == 0) blocksum[blockIdx.x] = ws[0] + ws[1] + ws[2] + ws[3];
}

__global__ __launch_bounds__(256) void scan_blocksums(int* __restrict__ blocksum, int nb) {
    __shared__ int sh[256];
    int t = threadIdx.x;
    sh[t] = (t < nb) ? blocksum[t] : 0;
    __syncthreads();
#pragma unroll
    for (int off = 1; off < 256; off <<= 1) {
        int v = (t >= off) ? sh[t - off] : 0;
        __syncthreads();
        sh[t] += v;
        __syncthreads();
    }
    if (t < nb) blocksum[t] = (t == 0) ? 0 : sh[t - 1];
}

__global__ __launch_bounds__(256) void scan_final(const int* __restrict__ cnt,
                                                  const int* __restrict__ blockoff,
                                                  int n, int* __restrict__ rowptr,
                                                  float* __restrict__ dinv) {
    int base = blockIdx.x * 1024;
    int t = threadIdx.x;
    int v[4];
    int s = 0;
#pragma unroll
    for (int j = 0; j < 4; ++j) {
        int i = base + (t << 2) + j;
        v[j] = (i < n) ? cnt[i] : 0;
        s += v[j];
    }
    __shared__ int sh[256];
    sh[t] = s;
    __syncthreads();
#pragma unroll
    for (int off = 1; off < 256; off <<= 1) {
        int x = (t >= off) ? sh[t - off] : 0;
        __syncthreads();
        sh[t] += x;
        __syncthreads();
    }
    int run = blockoff[blockIdx.x] + (sh[t] - s);
#pragma unroll
    for (int j = 0; j < 4; ++j) {
        int i = base + (t << 2) + j;
        if (i < n) {
            rowptr[i] = run;
            dinv[i] = rsqrtf((float)(v[j] + 1));  // +1 self-loop
            run += v[j];
        }
    }
    if (base + (t << 2) < n && n <= base + (t << 2) + 4) rowptr[n] = run;
}

// Pass 2: no atomics — position is rowptr[d] + rank[e]; store is fire-and-forget.
__global__ void fill_scatter(const int* __restrict__ ei, int E,
                             const int* __restrict__ rowptr,
                             const int* __restrict__ rank,
                             int* __restrict__ srcs, int n) {
    int e = blockIdx.x * blockDim.x + threadIdx.x;
    if (e < E) {
        int s = ei[e];
        int d = ei[E + e];
        if ((unsigned)d < (unsigned)n && (unsigned)s < (unsigned)n)
            srcs[rowptr[d] + rank[e]] = s;
    }
}

// ---------------- GEMM: G16[r][c] = bf16( (X[r]·W[:,c]) * dinv[r] ) ----------------

template <int M>
__global__ __launch_bounds__(256) void gemm_scale_bf16(const float* __restrict__ X,
                                                       const float* __restrict__ W,
                                                       const float* __restrict__ dinv,
                                                       unsigned short* __restrict__ G16,
                                                       int n) {
    constexpr int K = 128;
    constexpr int ROWS = 32;
    __shared__ float Xs[ROWS * K];  // 16 KB
    int t = threadIdx.x;
    int block_row = blockIdx.x * ROWS;

    {
        const float4* X4 = (const float4*)(X + (size_t)block_row * K);
        float4* Xs4 = (float4*)Xs;
        for (int i = t; i < ROWS * K / 4; i += 256) Xs4[i] = X4[i];
    }
    __syncthreads();

    constexpr int NCG = M / 4;     // float4 col-groups
    constexpr int RG = 256 / NCG;  // row groups
    constexpr int RPT = ROWS / RG; // rows per thread
    int cg = t % NCG;
    int rg = t / NCG;

    float4 acc[RPT];
#pragma unroll
    for (int j = 0; j < RPT; ++j) acc[j] = make_float4(0.f, 0.f, 0.f, 0.f);

    const float4* W4 = (const float4*)W;
#pragma unroll 4
    for (int k = 0; k < K; ++k) {
        float4 w = W4[k * NCG + cg];
#pragma unroll
        for (int j = 0; j < RPT; ++j) {
            float xv = Xs[(rg + j * RG) * K + k];
            acc[j].x += xv * w.x;
            acc[j].y += xv * w.y;
            acc[j].z += xv * w.z;
            acc[j].w += xv * w.w;
        }
    }

#pragma unroll
    for (int j = 0; j < RPT; ++j) {
        int r = block_row + rg + j * RG;
        if (r < n) {
            float di = dinv[r];
            ushort4 v;
            v.x = f2bf(acc[j].x * di);
            v.y = f2bf(acc[j].y * di);
            v.z = f2bf(acc[j].z * di);
            v.w = f2bf(acc[j].w * di);
            ((ushort4*)(G16 + (size_t)r * M))[cg] = v;
        }
    }
}

// ---------------- Aggregation (bf16 table, fp32 accumulate) ----------------

__global__ __launch_bounds__(256) void agg_d128(const unsigned short* __restrict__ G16,
                                                const int* __restrict__ srcs,
                                                const int* __restrict__ rowptr,
                                                const float* __restrict__ dinv,
                                                const float* __restrict__ bias,
                                                float* __restrict__ out, int n,
                                                int do_relu) {
    int wid = (blockIdx.x * blockDim.x + threadIdx.x) >> 6;
    int lane = threadIdx.x & 63;
    if (wid >= n) return;

    const unsigned* rowp = (const unsigned*)(G16 + (size_t)wid * 128);
    unsigned u = rowp[lane];  // self-loop
    float accx = bf_lo(u), accy = bf_hi(u);

    int beg = rowptr[wid], end = rowptr[wid + 1];
    for (int base = beg; base < end; base += 64) {
        int m = end - base;
        if (m > 64) m = 64;
        int sv = (base + lane < end) ? srcs[base + lane] : 0;
        for (int j = 0; j < m; ++j) {
            int s = __shfl(sv, j);
            unsigned g = ((const unsigned*)(G16 + (size_t)s * 128))[lane];
            accx += bf_lo(g);
            accy += bf_hi(g);
        }
    }
    float di = dinv[wid];
    float2 b = ((const float2*)bias)[lane];
    float ox = accx * di + b.x;
    float oy = accy * di + b.y;
    if (do_relu) {
        ox = fmaxf(ox, 0.f);
        oy = fmaxf(oy, 0.f);
    }
    ((float2*)(out + (size_t)wid * 128))[lane] = make_float2(ox, oy);
}

__global__ __launch_bounds__(256) void agg_d64(const unsigned short* __restrict__ G16,
                                               const int* __restrict__ srcs,
                                               const int* __restrict__ rowptr,
                                               const float* __restrict__ dinv,
                                               const float* __restrict__ bias,
                                               float* __restrict__ out, int n) {
    int wid = (blockIdx.x * blockDim.x + threadIdx.x) >> 6;
    int lane = threadIdx.x & 63;
    if (wid >= n) return;

    float acc = __uint_as_float(((unsigned)G16[(size_t)wid * 64 + lane]) << 16);

    int beg = rowptr[wid], end = rowptr[wid + 1];
    for (int base = beg; base < end; base += 64) {
        int m = end - base;
        if (m > 64) m = 64;
        int sv = (base + lane < end) ? srcs[base + lane] : 0;
        for (int j = 0; j < m; ++j) {
            int s = __shfl(sv, j);
            acc += __uint_as_float(((unsigned)G16[(size_t)s * 64 + lane]) << 16);
        }
    }
    out[(size_t)wid * 64 + lane] = acc * dinv[wid] + bias[lane];
}

// ---------------- launch ----------------

extern "C" void kernel_launch(void* const* d_in, const int* in_sizes, int n_in,
                              void* d_out, int out_size, void* d_ws, size_t ws_size,
                              hipStream_t stream) {
    const float* x = (const float*)d_in[0];
    const int* ei = (const int*)d_in[1];
    const float* W1 = (const float*)d_in[2];
    const float* b1 = (const float*)d_in[3];
    const float* W2 = (const float*)d_in[4];
    const float* b2 = (const float*)d_in[5];
    float* out = (float*)d_out;

    const int n = in_sizes[0] / 128;  // 100000
    const int E = in_sizes[1] / 2;    // 1600000

    char* ws = (char*)d_ws;
    size_t off = 0;
    auto alloc = [&](size_t bytes) {
        void* p = ws + off;
        off = (off + bytes + 255) & ~(size_t)255;
        return p;
    };
    unsigned short* g1 = (unsigned short*)alloc((size_t)n * 128 * 2);  // bf16 gather table
    float* a1 = (float*)alloc((size_t)n * 128 * 4);                    // relu(layer1 out)
    int* cnt = (int*)alloc((size_t)n * 4);
    int* rowptr = (int*)alloc(((size_t)n + 1) * 4);
    float* dinv = (float*)alloc((size_t)n * 4);
    int* srcs = (int*)alloc((size_t)E * 4);
    int* rank = (int*)alloc((size_t)E * 4);
    int* blocksum = (int*)alloc(1024 * 4);
    unsigned short* g2 = g1;  // reuse for layer 2 (12.8 MB <= 25.6 MB)

    const int nb_scan = (n + 1023) / 1024;  // 98 blocks, <=256 required
    int eb = (E + 255) / 256;

    hipMemsetAsync(cnt, 0, (size_t)n * 4, stream);

    count_rank<<<eb, 256, 0, stream>>>(ei, E, cnt, rank, n);
    scan_partial<<<nb_scan, 256, 0, stream>>>(cnt, n, blocksum);
    scan_blocksums<<<1, 256, 0, stream>>>(blocksum, nb_scan);
    scan_final<<<nb_scan, 256, 0, stream>>>(cnt, blocksum, n, rowptr, dinv);
    fill_scatter<<<eb, 256, 0, stream>>>(ei, E, rowptr, rank, srcs, n);

    // layer 1
    gemm_scale_bf16<128><<<(n + 31) / 32, 256, 0, stream>>>(x, W1, dinv, g1, n);
    agg_d128<<<(n + 3) / 4, 256, 0, stream>>>(g1, srcs, rowptr, dinv, b1, a1, n, 1);

    // layer 2
    gemm_scale_bf16<64><<<(n + 31) / 32, 256, 0, stream>>>(a1, W2, dinv, g2, n);
    agg_d64<<<(n + 3) / 4, 256, 0, stream>>>(g2, srcs, rowptr, dinv, b2, out, n);
}

// Round 6
// 331.375 us; speedup vs baseline: 2.2506x; 1.2956x over previous
//
#include <hip/hip_runtime.h>

// ---------------- bf16 helpers (hand-rolled RNE) ----------------

__device__ __forceinline__ unsigned short f2bf(float f) {
    unsigned u = __float_as_uint(f);
    u += 0x7fffu + ((u >> 16) & 1u);
    return (unsigned short)(u >> 16);
}
__device__ __forceinline__ float bf_lo(unsigned u) {  // low 16 bits -> float
    return __uint_as_float(u << 16);
}
__device__ __forceinline__ float bf_hi(unsigned u) {  // high 16 bits -> float
    return __uint_as_float(u & 0xffff0000u);
}

// ---------------- CSR build ----------------
// Pass 1: per-dst counts AND per-edge rank from the same atomic.
__global__ void count_rank(const int* __restrict__ ei, int E,
                           int* __restrict__ cnt, int* __restrict__ rank, int n) {
    int e = blockIdx.x * blockDim.x + threadIdx.x;
    if (e < E) {
        int d = ei[E + e];  // dst row (int32 per harness contract)
        if ((unsigned)d < (unsigned)n) rank[e] = atomicAdd(&cnt[d], 1);
    }
}

// ---- 3-phase parallel exclusive scan over cnt[0..n) -> rowptr[0..n], dinv ----
__global__ __launch_bounds__(256) void scan_partial(const int* __restrict__ cnt,
                                                    int n, int* __restrict__ blocksum) {
    int base = blockIdx.x * 1024;
    int t = threadIdx.x;
    int s = 0;
#pragma unroll
    for (int j = 0; j < 4; ++j) {
        int i = base + (t << 2) + j;
        if (i < n) s += cnt[i];
    }
#pragma unroll
    for (int off = 1; off < 64; off <<= 1) s += __shfl_xor(s, off);
    __shared__ int ws[4];
    if ((t & 63) == 0) ws[t >> 6] = s;
    __syncthreads();
    if (t == 0) blocksum[blockIdx.x] = ws[0] + ws[1] + ws[2] + ws[3];
}

__global__ __launch_bounds__(256) void scan_blocksums(int* __restrict__ blocksum, int nb) {
    __shared__ int sh[256];
    int t = threadIdx.x;
    sh[t] = (t < nb) ? blocksum[t] : 0;
    __syncthreads();
#pragma unroll
    for (int off = 1; off < 256; off <<= 1) {
        int v = (t >= off) ? sh[t - off] : 0;
        __syncthreads();
        sh[t] += v;
        __syncthreads();
    }
    if (t < nb) blocksum[t] = (t == 0) ? 0 : sh[t - 1];
}

__global__ __launch_bounds__(256) void scan_final(const int* __restrict__ cnt,
                                                  const int* __restrict__ blockoff,
                                                  int n, int* __restrict__ rowptr,
                                                  float* __restrict__ dinv) {
    int base = blockIdx.x * 1024;
    int t = threadIdx.x;
    int v[4];
    int s = 0;
#pragma unroll
    for (int j = 0; j < 4; ++j) {
        int i = base + (t << 2) + j;
        v[j] = (i < n) ? cnt[i] : 0;
        s += v[j];
    }
    __shared__ int sh[256];
    sh[t] = s;
    __syncthreads();
#pragma unroll
    for (int off = 1; off < 256; off <<= 1) {
        int x = (t >= off) ? sh[t - off] : 0;
        __syncthreads();
        sh[t] += x;
        __syncthreads();
    }
    int run = blockoff[blockIdx.x] + (sh[t] - s);
#pragma unroll
    for (int j = 0; j < 4; ++j) {
        int i = base + (t << 2) + j;
        if (i < n) {
            rowptr[i] = run;
            dinv[i] = rsqrtf((float)(v[j] + 1));  // +1 self-loop
            run += v[j];
        }
    }
    if (base + (t << 2) < n && n <= base + (t << 2) + 4) rowptr[n] = run;
}

// Pass 2: no atomics — position is rowptr[d] + rank[e]; store is fire-and-forget.
__global__ void fill_scatter(const int* __restrict__ ei, int E,
                             const int* __restrict__ rowptr,
                             const int* __restrict__ rank,
                             int* __restrict__ srcs, int n) {
    int e = blockIdx.x * blockDim.x + threadIdx.x;
    if (e < E) {
        int s = ei[e];
        int d = ei[E + e];
        if ((unsigned)d < (unsigned)n && (unsigned)s < (unsigned)n)
            srcs[rowptr[d] + rank[e]] = s;
    }
}

// ---------------- GEMM: G16[r][c] = bf16( (X[r]·W[:,c]) * dinv[r] ) ----------------

template <int M>
__global__ __launch_bounds__(256) void gemm_scale_bf16(const float* __restrict__ X,
                                                       const float* __restrict__ W,
                                                       const float* __restrict__ dinv,
                                                       unsigned short* __restrict__ G16,
                                                       int n) {
    constexpr int K = 128;
    constexpr int ROWS = 32;
    __shared__ float Xs[ROWS * K];  // 16 KB
    int t = threadIdx.x;
    int block_row = blockIdx.x * ROWS;

    {
        const float4* X4 = (const float4*)(X + (size_t)block_row * K);
        float4* Xs4 = (float4*)Xs;
        for (int i = t; i < ROWS * K / 4; i += 256) Xs4[i] = X4[i];
    }
    __syncthreads();

    constexpr int NCG = M / 4;     // float4 col-groups
    constexpr int RG = 256 / NCG;  // row groups
    constexpr int RPT = ROWS / RG; // rows per thread
    int cg = t % NCG;
    int rg = t / NCG;

    float4 acc[RPT];
#pragma unroll
    for (int j = 0; j < RPT; ++j) acc[j] = make_float4(0.f, 0.f, 0.f, 0.f);

    const float4* W4 = (const float4*)W;
#pragma unroll 4
    for (int k = 0; k < K; ++k) {
        float4 w = W4[k * NCG + cg];
#pragma unroll
        for (int j = 0; j < RPT; ++j) {
            float xv = Xs[(rg + j * RG) * K + k];
            acc[j].x += xv * w.x;
            acc[j].y += xv * w.y;
            acc[j].z += xv * w.z;
            acc[j].w += xv * w.w;
        }
    }

#pragma unroll
    for (int j = 0; j < RPT; ++j) {
        int r = block_row + rg + j * RG;
        if (r < n) {
            float di = dinv[r];
            ushort4 v;
            v.x = f2bf(acc[j].x * di);
            v.y = f2bf(acc[j].y * di);
            v.z = f2bf(acc[j].z * di);
            v.w = f2bf(acc[j].w * di);
            ((ushort4*)(G16 + (size_t)r * M))[cg] = v;
        }
    }
}

// ---------------- Aggregation (bf16 table, fp32 accumulate) ----------------
// Lane-group gather: 4 (d128) / 8 (d64) src rows in flight per load instruction.

__global__ __launch_bounds__(256) void agg_d128(const unsigned short* __restrict__ G16,
                                                const int* __restrict__ srcs,
                                                const int* __restrict__ rowptr,
                                                const float* __restrict__ dinv,
                                                const float* __restrict__ bias,
                                                float* __restrict__ out, int n,
                                                int do_relu) {
    int wid = (blockIdx.x * blockDim.x + threadIdx.x) >> 6;
    int lane = threadIdx.x & 63;
    if (wid >= n) return;
    int g = lane >> 4;    // group 0..3: which neighbor within a quad
    int lh = lane & 15;   // 16 lanes x 16 B = one 256 B row

    float acc[8];
    {   // self-loop: group 0 reads the self row, others start at zero
        uint4 u = make_uint4(0u, 0u, 0u, 0u);
        if (g == 0) u = ((const uint4*)(G16 + (size_t)wid * 128))[lh];
        acc[0] = bf_lo(u.x); acc[1] = bf_hi(u.x);
        acc[2] = bf_lo(u.y); acc[3] = bf_hi(u.y);
        acc[4] = bf_lo(u.z); acc[5] = bf_hi(u.z);
        acc[6] = bf_lo(u.w); acc[7] = bf_hi(u.w);
    }

    int beg = rowptr[wid], end = rowptr[wid + 1];
    for (int base = beg; base < end; base += 64) {
        int m = end - base;
        if (m > 64) m = 64;
        int sv = (base + lane < end) ? srcs[base + lane] : 0;
        for (int j = 0; j < m; j += 4) {
            int s = __shfl(sv, j + g);          // group g takes neighbor j+g
            uint4 u = ((const uint4*)(G16 + (size_t)s * 128))[lh];
            if (j + g >= m) u = make_uint4(0u, 0u, 0u, 0u);
            acc[0] += bf_lo(u.x); acc[1] += bf_hi(u.x);
            acc[2] += bf_lo(u.y); acc[3] += bf_hi(u.y);
            acc[4] += bf_lo(u.z); acc[5] += bf_hi(u.z);
            acc[6] += bf_lo(u.w); acc[7] += bf_hi(u.w);
        }
    }

#pragma unroll
    for (int k = 0; k < 8; ++k) {  // combine the 4 group partials
        acc[k] += __shfl_xor(acc[k], 16);
        acc[k] += __shfl_xor(acc[k], 32);
    }

    if (g < 2) {  // 32 lanes write the 512 B output row
        float di = dinv[wid];
        int idx = 2 * lh + g;  // float4 index in the row
        float4 b = ((const float4*)bias)[idx];
        int k0 = 4 * g;
        float4 o;
        o.x = acc[k0 + 0] * di + b.x;
        o.y = acc[k0 + 1] * di + b.y;
        o.z = acc[k0 + 2] * di + b.z;
        o.w = acc[k0 + 3] * di + b.w;
        if (do_relu) {
            o.x = fmaxf(o.x, 0.f); o.y = fmaxf(o.y, 0.f);
            o.z = fmaxf(o.z, 0.f); o.w = fmaxf(o.w, 0.f);
        }
        ((float4*)(out + (size_t)wid * 128))[idx] = o;
    }
}

__global__ __launch_bounds__(256) void agg_d64(const unsigned short* __restrict__ G16,
                                               const int* __restrict__ srcs,
                                               const int* __restrict__ rowptr,
                                               const float* __restrict__ dinv,
                                               const float* __restrict__ bias,
                                               float* __restrict__ out, int n) {
    int wid = (blockIdx.x * blockDim.x + threadIdx.x) >> 6;
    int lane = threadIdx.x & 63;
    if (wid >= n) return;
    int g = lane >> 3;   // group 0..7: which neighbor within an octet
    int lh = lane & 7;   // 8 lanes x 16 B = one 128 B row

    float acc[8];
    {   // self-loop
        uint4 u = make_uint4(0u, 0u, 0u, 0u);
        if (g == 0) u = ((const uint4*)(G16 + (size_t)wid * 64))[lh];
        acc[0] = bf_lo(u.x); acc[1] = bf_hi(u.x);
        acc[2] = bf_lo(u.y); acc[3] = bf_hi(u.y);
        acc[4] = bf_lo(u.z); acc[5] = bf_hi(u.z);
        acc[6] = bf_lo(u.w); acc[7] = bf_hi(u.w);
    }

    int beg = rowptr[wid], end = rowptr[wid + 1];
    for (int base = beg; base < end; base += 64) {
        int m = end - base;
        if (m > 64) m = 64;
        int sv = (base + lane < end) ? srcs[base + lane] : 0;
        for (int j = 0; j < m; j += 8) {
            int s = __shfl(sv, j + g);
            uint4 u = ((const uint4*)(G16 + (size_t)s * 64))[lh];
            if (j + g >= m) u = make_uint4(0u, 0u, 0u, 0u);
            acc[0] += bf_lo(u.x); acc[1] += bf_hi(u.x);
            acc[2] += bf_lo(u.y); acc[3] += bf_hi(u.y);
            acc[4] += bf_lo(u.z); acc[5] += bf_hi(u.z);
            acc[6] += bf_lo(u.w); acc[7] += bf_hi(u.w);
        }
    }

#pragma unroll
    for (int k = 0; k < 8; ++k) {  // combine the 8 group partials
        acc[k] += __shfl_xor(acc[k], 8);
        acc[k] += __shfl_xor(acc[k], 16);
        acc[k] += __shfl_xor(acc[k], 32);
    }

    if (g < 2) {  // 16 lanes write the 256 B output row
        float di = dinv[wid];
        int idx = 2 * lh + g;
        float4 b = ((const float4*)bias)[idx];
        int k0 = 4 * g;
        float4 o;
        o.x = acc[k0 + 0] * di + b.x;
        o.y = acc[k0 + 1] * di + b.y;
        o.z = acc[k0 + 2] * di + b.z;
        o.w = acc[k0 + 3] * di + b.w;
        ((float4*)(out + (size_t)wid * 64))[idx] = o;
    }
}

// ---------------- launch ----------------

extern "C" void kernel_launch(void* const* d_in, const int* in_sizes, int n_in,
                              void* d_out, int out_size, void* d_ws, size_t ws_size,
                              hipStream_t stream) {
    const float* x = (const float*)d_in[0];
    const int* ei = (const int*)d_in[1];
    const float* W1 = (const float*)d_in[2];
    const float* b1 = (const float*)d_in[3];
    const float* W2 = (const float*)d_in[4];
    const float* b2 = (const float*)d_in[5];
    float* out = (float*)d_out;

    const int n = in_sizes[0] / 128;  // 100000
    const int E = in_sizes[1] / 2;    // 1600000

    char* ws = (char*)d_ws;
    size_t off = 0;
    auto alloc = [&](size_t bytes) {
        void* p = ws + off;
        off = (off + bytes + 255) & ~(size_t)255;
        return p;
    };
    unsigned short* g1 = (unsigned short*)alloc((size_t)n * 128 * 2);  // bf16 gather table
    float* a1 = (float*)alloc((size_t)n * 128 * 4);                    // relu(layer1 out)
    int* cnt = (int*)alloc((size_t)n * 4);
    int* rowptr = (int*)alloc(((size_t)n + 1) * 4);
    float* dinv = (float*)alloc((size_t)n * 4);
    int* srcs = (int*)alloc((size_t)E * 4);
    int* rank = (int*)alloc((size_t)E * 4);
    int* blocksum = (int*)alloc(1024 * 4);
    unsigned short* g2 = g1;  // reuse for layer 2 (12.8 MB <= 25.6 MB)

    const int nb_scan = (n + 1023) / 1024;  // 98 blocks, <=256 required
    int eb = (E + 255) / 256;

    hipMemsetAsync(cnt, 0, (size_t)n * 4, stream);

    count_rank<<<eb, 256, 0, stream>>>(ei, E, cnt, rank, n);
    scan_partial<<<nb_scan, 256, 0, stream>>>(cnt, n, blocksum);
    scan_blocksums<<<1, 256, 0, stream>>>(blocksum, nb_scan);
    scan_final<<<nb_scan, 256, 0, stream>>>(cnt, blocksum, n, rowptr, dinv);
    fill_scatter<<<eb, 256, 0, stream>>>(ei, E, rowptr, rank, srcs, n);

    // layer 1
    gemm_scale_bf16<128><<<(n + 31) / 32, 256, 0, stream>>>(x, W1, dinv, g1, n);
    agg_d128<<<(n + 3) / 4, 256, 0, stream>>>(g1, srcs, rowptr, dinv, b1, a1, n, 1);

    // layer 2
    gemm_scale_bf16<64><<<(n + 31) / 32, 256, 0, stream>>>(a1, W2, dinv, g2, n);
    agg_d64<<<(n + 3) / 4, 256, 0, stream>>>(g2, srcs, rowptr, dinv, b2, out, n);
}

// Round 7
// 320.917 us; speedup vs baseline: 2.3239x; 1.0326x over previous
//
#include <hip/hip_runtime.h>

typedef __attribute__((ext_vector_type(8))) short bf16x8;
typedef __attribute__((ext_vector_type(4))) float f32x4;

// ---------------- bf16 helpers (hand-rolled RNE) ----------------

__device__ __forceinline__ unsigned short f2bf(float f) {
    unsigned u = __float_as_uint(f);
    u += 0x7fffu + ((u >> 16) & 1u);
    return (unsigned short)(u >> 16);
}
__device__ __forceinline__ float bf_lo(unsigned u) { return __uint_as_float(u << 16); }
__device__ __forceinline__ float bf_hi(unsigned u) { return __uint_as_float(u & 0xffff0000u); }

// ---------------- CSR build ----------------

__global__ void count_rank(const int* __restrict__ ei, int E,
                           int* __restrict__ cnt, int* __restrict__ rank, int n) {
    int e = blockIdx.x * blockDim.x + threadIdx.x;
    if (e < E) {
        int d = ei[E + e];
        if ((unsigned)d < (unsigned)n) rank[e] = atomicAdd(&cnt[d], 1);
    }
}

__global__ __launch_bounds__(256) void scan_partial(const int* __restrict__ cnt,
                                                    int n, int* __restrict__ blocksum) {
    int base = blockIdx.x * 1024;
    int t = threadIdx.x;
    int s = 0;
#pragma unroll
    for (int j = 0; j < 4; ++j) {
        int i = base + (t << 2) + j;
        if (i < n) s += cnt[i];
    }
#pragma unroll
    for (int off = 1; off < 64; off <<= 1) s += __shfl_xor(s, off);
    __shared__ int ws[4];
    if ((t & 63) == 0) ws[t >> 6] = s;
    __syncthreads();
    if (t == 0) blocksum[blockIdx.x] = ws[0] + ws[1] + ws[2] + ws[3];
}

__global__ __launch_bounds__(256) void scan_blocksums(int* __restrict__ blocksum, int nb) {
    __shared__ int sh[256];
    int t = threadIdx.x;
    sh[t] = (t < nb) ? blocksum[t] : 0;
    __syncthreads();
#pragma unroll
    for (int off = 1; off < 256; off <<= 1) {
        int v = (t >= off) ? sh[t - off] : 0;
        __syncthreads();
        sh[t] += v;
        __syncthreads();
    }
    if (t < nb) blocksum[t] = (t == 0) ? 0 : sh[t - 1];
}

__global__ __launch_bounds__(256) void scan_final(const int* __restrict__ cnt,
                                                  const int* __restrict__ blockoff,
                                                  int n, int* __restrict__ rowptr,
                                                  float* __restrict__ dinv) {
    int base = blockIdx.x * 1024;
    int t = threadIdx.x;
    int v[4];
    int s = 0;
#pragma unroll
    for (int j = 0; j < 4; ++j) {
        int i = base + (t << 2) + j;
        v[j] = (i < n) ? cnt[i] : 0;
        s += v[j];
    }
    __shared__ int sh[256];
    sh[t] = s;
    __syncthreads();
#pragma unroll
    for (int off = 1; off < 256; off <<= 1) {
        int x = (t >= off) ? sh[t - off] : 0;
        __syncthreads();
        sh[t] += x;
        __syncthreads();
    }
    int run = blockoff[blockIdx.x] + (sh[t] - s);
#pragma unroll
    for (int j = 0; j < 4; ++j) {
        int i = base + (t << 2) + j;
        if (i < n) {
            rowptr[i] = run;
            dinv[i] = rsqrtf((float)(v[j] + 1));
            run += v[j];
        }
    }
    if (base + (t << 2) < n && n <= base + (t << 2) + 4) rowptr[n] = run;
}

__global__ void fill_scatter(const int* __restrict__ ei, int E,
                             const int* __restrict__ rowptr,
                             const int* __restrict__ rank,
                             int* __restrict__ srcs, int n) {
    int e = blockIdx.x * blockDim.x + threadIdx.x;
    if (e < E) {
        int s = ei[e];
        int d = ei[E + e];
        if ((unsigned)d < (unsigned)n && (unsigned)s < (unsigned)n)
            srcs[rowptr[d] + rank[e]] = s;
    }
}

// ---------------- MFMA GEMM: G16[r][c] = bf16( (X[r]·W[:,c]) * dinv[r] ) ----------------
// K = 128. Block = 256 thr (4 waves), BM = 64 rows, full M cols.
// mfma_f32_16x16x32_bf16 frag layout (gfx950, verified m89/m91/m156):
//   A: lane l holds A[row = l&15][k = 4*(l>>4) + (j&3) + 16*(j>>2)], j = 0..7
//   B: lane l holds B[k same pattern][col = l&15]
//   D: lane l reg q = D[row = (l>>4)*4 + q][col = l&15]
// LDS XOR-swizzle ((row&7)<<4 on byte addr) kills the 256B-stride bank conflict (G4/T2).

template <int M, bool IN_BF16>
__global__ __launch_bounds__(256) void gemm_mfma(const void* __restrict__ Xv,
                                                 const float* __restrict__ W,
                                                 const float* __restrict__ dinv,
                                                 unsigned short* __restrict__ G16,
                                                 int n) {
    constexpr int K = 128;
    constexpr int BM = 64;
    __shared__ unsigned short Xs[BM * K];  // [m][k], byte addr ^ ((m&7)<<4)
    __shared__ unsigned short Wt[M * K];   // [c][k], byte addr ^ ((c&7)<<4)
    int t = threadIdx.x;
    int blockRow = blockIdx.x * BM;

    // ---- stage X tile (convert to bf16 if needed) ----
    if (!IN_BF16) {
        const float* X = (const float*)Xv;
#pragma unroll
        for (int i = 0; i < 8; ++i) {       // 64 rows * 32 float4
            int f = t + i * 256;
            int m = f >> 5, k4 = f & 31;
            float4 v = make_float4(0.f, 0.f, 0.f, 0.f);
            if (blockRow + m < n) v = ((const float4*)(X + (size_t)(blockRow + m) * K))[k4];
            uint2 p;
            p.x = (unsigned)f2bf(v.x) | ((unsigned)f2bf(v.y) << 16);
            p.y = (unsigned)f2bf(v.z) | ((unsigned)f2bf(v.w) << 16);
            int addr = (m * 256 + k4 * 8) ^ ((m & 7) << 4);
            *(uint2*)((char*)Xs + addr) = p;
        }
    } else {
        const unsigned short* X = (const unsigned short*)Xv;
#pragma unroll
        for (int i = 0; i < 4; ++i) {       // 64 rows * 16 uint4
            int f = t + i * 256;
            int m = f >> 4, k8 = f & 15;
            uint4 v = make_uint4(0u, 0u, 0u, 0u);
            if (blockRow + m < n) v = ((const uint4*)(X + (size_t)(blockRow + m) * K))[k8];
            int addr = (m * 256 + k8 * 16) ^ ((m & 7) << 4);
            *(uint4*)((char*)Xs + addr) = v;
        }
    }

    // ---- stage W transposed [c][k] ----
#pragma unroll
    for (int i = 0; i < M / 8; ++i) {       // M * 32 (c, k4) pairs
        int f = t + i * 256;
        int c = f >> 5, k4 = f & 31;
        unsigned short h[4];
#pragma unroll
        for (int q = 0; q < 4; ++q) h[q] = f2bf(W[(size_t)(4 * k4 + q) * M + c]);
        uint2 p;
        p.x = (unsigned)h[0] | ((unsigned)h[1] << 16);
        p.y = (unsigned)h[2] | ((unsigned)h[3] << 16);
        int addr = (c * 256 + k4 * 8) ^ ((c & 7) << 4);
        *(uint2*)((char*)Wt + addr) = p;
    }
    __syncthreads();

    int w = t >> 6, l = t & 63;
    int lg = l >> 4, lm = l & 15;
    constexpr int NCT = M / 16;

    union F8 { uint2 u2[2]; bf16x8 v; };

    // A frags for this wave's 16-row tile
    bf16x8 afr[4];
    int mrow = 16 * w + lm;
    int swa = (mrow & 7) << 4;
#pragma unroll
    for (int kk = 0; kk < 4; ++kk) {
        int pa = mrow * 256 + (32 * kk + 4 * lg) * 2;
        F8 a;
        a.u2[0] = *(const uint2*)((const char*)Xs + (pa ^ swa));
        a.u2[1] = *(const uint2*)((const char*)Xs + ((pa + 32) ^ swa));
        afr[kk] = a.v;
    }

    f32x4 acc[NCT];
#pragma unroll
    for (int ct = 0; ct < NCT; ++ct) acc[ct] = (f32x4){0.f, 0.f, 0.f, 0.f};

#pragma unroll
    for (int ct = 0; ct < NCT; ++ct) {
        int c = ct * 16 + lm;
        int swc = (c & 7) << 4;
#pragma unroll
        for (int kk = 0; kk < 4; ++kk) {
            int pb = c * 256 + (32 * kk + 4 * lg) * 2;
            F8 b;
            b.u2[0] = *(const uint2*)((const char*)Wt + (pb ^ swc));
            b.u2[1] = *(const uint2*)((const char*)Wt + ((pb + 32) ^ swc));
            acc[ct] = __builtin_amdgcn_mfma_f32_16x16x32_bf16(afr[kk], b.v, acc[ct], 0, 0, 0);
        }
    }

    // ---- epilogue: scale by dinv, emit bf16 ----
    float dv[4];
#pragma unroll
    for (int q = 0; q < 4; ++q) {
        int r = blockRow + 16 * w + 4 * lg + q;
        dv[q] = (r < n) ? dinv[r] : 0.f;
    }
#pragma unroll
    for (int ct = 0; ct < NCT; ++ct) {
#pragma unroll
        for (int q = 0; q < 4; ++q) {
            int r = blockRow + 16 * w + 4 * lg + q;
            if (r < n) G16[(size_t)r * M + ct * 16 + lm] = f2bf(acc[ct][q] * dv[q]);
        }
    }
}

// ---------------- Aggregation (bf16 table, fp32 accumulate) ----------------

// d128: writes a1 in bf16 (feeds bf16 MFMA gemm2 — identical rounding, half traffic)
__global__ __launch_bounds__(256) void agg_d128(const unsigned short* __restrict__ G16,
                                                const int* __restrict__ srcs,
                                                const int* __restrict__ rowptr,
                                                const float* __restrict__ dinv,
                                                const float* __restrict__ bias,
                                                unsigned short* __restrict__ out, int n) {
    int wid = (blockIdx.x * blockDim.x + threadIdx.x) >> 6;
    int lane = threadIdx.x & 63;
    if (wid >= n) return;
    int g = lane >> 4;
    int lh = lane & 15;

    float acc[8];
    {
        uint4 u = make_uint4(0u, 0u, 0u, 0u);
        if (g == 0) u = ((const uint4*)(G16 + (size_t)wid * 128))[lh];
        acc[0] = bf_lo(u.x); acc[1] = bf_hi(u.x);
        acc[2] = bf_lo(u.y); acc[3] = bf_hi(u.y);
        acc[4] = bf_lo(u.z); acc[5] = bf_hi(u.z);
        acc[6] = bf_lo(u.w); acc[7] = bf_hi(u.w);
    }

    int beg = rowptr[wid], end = rowptr[wid + 1];
    for (int base = beg; base < end; base += 64) {
        int m = end - base;
        if (m > 64) m = 64;
        int sv = (base + lane < end) ? srcs[base + lane] : 0;
        for (int j = 0; j < m; j += 4) {
            int s = __shfl(sv, j + g);
            uint4 u = ((const uint4*)(G16 + (size_t)s * 128))[lh];
            if (j + g >= m) u = make_uint4(0u, 0u, 0u, 0u);
            acc[0] += bf_lo(u.x); acc[1] += bf_hi(u.x);
            acc[2] += bf_lo(u.y); acc[3] += bf_hi(u.y);
            acc[4] += bf_lo(u.z); acc[5] += bf_hi(u.z);
            acc[6] += bf_lo(u.w); acc[7] += bf_hi(u.w);
        }
    }

#pragma unroll
    for (int k = 0; k < 8; ++k) {
        acc[k] += __shfl_xor(acc[k], 16);
        acc[k] += __shfl_xor(acc[k], 32);
    }

    if (g < 2) {
        float di = dinv[wid];
        int idx = 2 * lh + g;  // 4-col group
        float4 b = ((const float4*)bias)[idx];
        int k0 = 4 * g;
        float o0 = fmaxf(acc[k0 + 0] * di + b.x, 0.f);
        float o1 = fmaxf(acc[k0 + 1] * di + b.y, 0.f);
        float o2 = fmaxf(acc[k0 + 2] * di + b.z, 0.f);
        float o3 = fmaxf(acc[k0 + 3] * di + b.w, 0.f);
        uint2 p;
        p.x = (unsigned)f2bf(o0) | ((unsigned)f2bf(o1) << 16);
        p.y = (unsigned)f2bf(o2) | ((unsigned)f2bf(o3) << 16);
        ((uint2*)(out + (size_t)wid * 128))[idx] = p;
    }
}

__global__ __launch_bounds__(256) void agg_d64(const unsigned short* __restrict__ G16,
                                               const int* __restrict__ srcs,
                                               const int* __restrict__ rowptr,
                                               const float* __restrict__ dinv,
                                               const float* __restrict__ bias,
                                               float* __restrict__ out, int n) {
    int wid = (blockIdx.x * blockDim.x + threadIdx.x) >> 6;
    int lane = threadIdx.x & 63;
    if (wid >= n) return;
    int g = lane >> 3;
    int lh = lane & 7;

    float acc[8];
    {
        uint4 u = make_uint4(0u, 0u, 0u, 0u);
        if (g == 0) u = ((const uint4*)(G16 + (size_t)wid * 64))[lh];
        acc[0] = bf_lo(u.x); acc[1] = bf_hi(u.x);
        acc[2] = bf_lo(u.y); acc[3] = bf_hi(u.y);
        acc[4] = bf_lo(u.z); acc[5] = bf_hi(u.z);
        acc[6] = bf_lo(u.w); acc[7] = bf_hi(u.w);
    }

    int beg = rowptr[wid], end = rowptr[wid + 1];
    for (int base = beg; base < end; base += 64) {
        int m = end - base;
        if (m > 64) m = 64;
        int sv = (base + lane < end) ? srcs[base + lane] : 0;
        for (int j = 0; j < m; j += 8) {
            int s = __shfl(sv, j + g);
            uint4 u = ((const uint4*)(G16 + (size_t)s * 64))[lh];
            if (j + g >= m) u = make_uint4(0u, 0u, 0u, 0u);
            acc[0] += bf_lo(u.x); acc[1] += bf_hi(u.x);
            acc[2] += bf_lo(u.y); acc[3] += bf_hi(u.y);
            acc[4] += bf_lo(u.z); acc[5] += bf_hi(u.z);
            acc[6] += bf_lo(u.w); acc[7] += bf_hi(u.w);
        }
    }

#pragma unroll
    for (int k = 0; k < 8; ++k) {
        acc[k] += __shfl_xor(acc[k], 8);
        acc[k] += __shfl_xor(acc[k], 16);
        acc[k] += __shfl_xor(acc[k], 32);
    }

    if (g < 2) {
        float di = dinv[wid];
        int idx = 2 * lh + g;
        float4 b = ((const float4*)bias)[idx];
        int k0 = 4 * g;
        float4 o;
        o.x = acc[k0 + 0] * di + b.x;
        o.y = acc[k0 + 1] * di + b.y;
        o.z = acc[k0 + 2] * di + b.z;
        o.w = acc[k0 + 3] * di + b.w;
        ((float4*)(out + (size_t)wid * 64))[idx] = o;
    }
}

// ---------------- launch ----------------

extern "C" void kernel_launch(void* const* d_in, const int* in_sizes, int n_in,
                              void* d_out, int out_size, void* d_ws, size_t ws_size,
                              hipStream_t stream) {
    const float* x = (const float*)d_in[0];
    const int* ei = (const int*)d_in[1];
    const float* W1 = (const float*)d_in[2];
    const float* b1 = (const float*)d_in[3];
    const float* W2 = (const float*)d_in[4];
    const float* b2 = (const float*)d_in[5];
    float* out = (float*)d_out;

    const int n = in_sizes[0] / 128;  // 100000
    const int E = in_sizes[1] / 2;    // 1600000

    char* ws = (char*)d_ws;
    size_t off = 0;
    auto alloc = [&](size_t bytes) {
        void* p = ws + off;
        off = (off + bytes + 255) & ~(size_t)255;
        return p;
    };
    unsigned short* g1 = (unsigned short*)alloc((size_t)n * 128 * 2);  // bf16 gather table
    unsigned short* a1 = (unsigned short*)alloc((size_t)n * 128 * 2);  // bf16 relu(layer1)
    int* cnt = (int*)alloc((size_t)n * 4);
    int* rowptr = (int*)alloc(((size_t)n + 1) * 4);
    float* dinv = (float*)alloc((size_t)n * 4);
    int* srcs = (int*)alloc((size_t)E * 4);
    int* rank = (int*)alloc((size_t)E * 4);
    int* blocksum = (int*)alloc(1024 * 4);
    unsigned short* g2 = g1;  // reuse for layer 2

    const int nb_scan = (n + 1023) / 1024;
    int eb = (E + 255) / 256;
    int gb = (n + 63) / 64;  // MFMA gemm blocks (BM=64)

    hipMemsetAsync(cnt, 0, (size_t)n * 4, stream);

    count_rank<<<eb, 256, 0, stream>>>(ei, E, cnt, rank, n);
    scan_partial<<<nb_scan, 256, 0, stream>>>(cnt, n, blocksum);
    scan_blocksums<<<1, 256, 0, stream>>>(blocksum, nb_scan);
    scan_final<<<nb_scan, 256, 0, stream>>>(cnt, blocksum, n, rowptr, dinv);
    fill_scatter<<<eb, 256, 0, stream>>>(ei, E, rowptr, rank, srcs, n);

    // layer 1
    gemm_mfma<128, false><<<gb, 256, 0, stream>>>(x, W1, dinv, g1, n);
    agg_d128<<<(n + 3) / 4, 256, 0, stream>>>(g1, srcs, rowptr, dinv, b1, a1, n);

    // layer 2
    gemm_mfma<64, true><<<gb, 256, 0, stream>>>(a1, W2, dinv, g2, n);
    agg_d64<<<(n + 3) / 4, 256, 0, stream>>>(g2, srcs, rowptr, dinv, b2, out, n);
}

// Round 8
// 319.823 us; speedup vs baseline: 2.3318x; 1.0034x over previous
//
#include <hip/hip_runtime.h>

typedef __attribute__((ext_vector_type(8))) short bf16x8;
typedef __attribute__((ext_vector_type(4))) float f32x4;

// ---------------- bf16 helpers (hand-rolled RNE) ----------------

__device__ __forceinline__ unsigned short f2bf(float f) {
    unsigned u = __float_as_uint(f);
    u += 0x7fffu + ((u >> 16) & 1u);
    return (unsigned short)(u >> 16);
}
__device__ __forceinline__ float bf_lo(unsigned u) { return __uint_as_float(u << 16); }
__device__ __forceinline__ float bf_hi(unsigned u) { return __uint_as_float(u & 0xffff0000u); }

// ---------------- CSR build ----------------

__global__ void count_rank(const int* __restrict__ ei, int E,
                           int* __restrict__ cnt, int* __restrict__ rank, int n) {
    int e = blockIdx.x * blockDim.x + threadIdx.x;
    if (e < E) {
        int d = ei[E + e];
        if ((unsigned)d < (unsigned)n) rank[e] = atomicAdd(&cnt[d], 1);
    }
}

__global__ __launch_bounds__(256) void scan_partial(const int* __restrict__ cnt,
                                                    int n, int* __restrict__ blocksum) {
    int base = blockIdx.x * 1024;
    int t = threadIdx.x;
    int s = 0;
#pragma unroll
    for (int j = 0; j < 4; ++j) {
        int i = base + (t << 2) + j;
        if (i < n) s += cnt[i];
    }
#pragma unroll
    for (int off = 1; off < 64; off <<= 1) s += __shfl_xor(s, off);
    __shared__ int ws[4];
    if ((t & 63) == 0) ws[t >> 6] = s;
    __syncthreads();
    if (t == 0) blocksum[blockIdx.x] = ws[0] + ws[1] + ws[2] + ws[3];
}

__global__ __launch_bounds__(256) void scan_blocksums(int* __restrict__ blocksum, int nb) {
    __shared__ int sh[256];
    int t = threadIdx.x;
    sh[t] = (t < nb) ? blocksum[t] : 0;
    __syncthreads();
#pragma unroll
    for (int off = 1; off < 256; off <<= 1) {
        int v = (t >= off) ? sh[t - off] : 0;
        __syncthreads();
        sh[t] += v;
        __syncthreads();
    }
    if (t < nb) blocksum[t] = (t == 0) ? 0 : sh[t - 1];
}

__global__ __launch_bounds__(256) void scan_final(const int* __restrict__ cnt,
                                                  const int* __restrict__ blockoff,
                                                  int n, int* __restrict__ rowptr,
                                                  float* __restrict__ dinv) {
    int base = blockIdx.x * 1024;
    int t = threadIdx.x;
    int v[4];
    int s = 0;
#pragma unroll
    for (int j = 0; j < 4; ++j) {
        int i = base + (t << 2) + j;
        v[j] = (i < n) ? cnt[i] : 0;
        s += v[j];
    }
    __shared__ int sh[256];
    sh[t] = s;
    __syncthreads();
#pragma unroll
    for (int off = 1; off < 256; off <<= 1) {
        int x = (t >= off) ? sh[t - off] : 0;
        __syncthreads();
        sh[t] += x;
        __syncthreads();
    }
    int run = blockoff[blockIdx.x] + (sh[t] - s);
#pragma unroll
    for (int j = 0; j < 4; ++j) {
        int i = base + (t << 2) + j;
        if (i < n) {
            rowptr[i] = run;
            dinv[i] = rsqrtf((float)(v[j] + 1));
            run += v[j];
        }
    }
    if (base + (t << 2) < n && n <= base + (t << 2) + 4) rowptr[n] = run;
}

__global__ void fill_scatter(const int* __restrict__ ei, int E,
                             const int* __restrict__ rowptr,
                             const int* __restrict__ rank,
                             int* __restrict__ srcs, int n) {
    int e = blockIdx.x * blockDim.x + threadIdx.x;
    if (e < E) {
        int s = ei[e];
        int d = ei[E + e];
        if ((unsigned)d < (unsigned)n && (unsigned)s < (unsigned)n)
            srcs[rowptr[d] + rank[e]] = s;
    }
}

// ---------------- one-time W -> bf16 transposed [c][k] ----------------
// Tiny (96 KB total); runs once per call, off the critical path cost-wise.

__global__ __launch_bounds__(256) void prep_w(const float* __restrict__ W1,
                                              const float* __restrict__ W2,
                                              unsigned short* __restrict__ Wt1,
                                              unsigned short* __restrict__ Wt2) {
    int t = blockIdx.x * blockDim.x + threadIdx.x;
    if (t < 128 * 128) {          // W1: [k][c] 128x128, coalesced read
        int k = t >> 7, c = t & 127;
        Wt1[c * 128 + k] = f2bf(W1[t]);
    } else if (t < 128 * 128 + 128 * 64) {  // W2: [k][c] 128x64
        int i = t - 128 * 128;
        int k = i >> 6, c = i & 63;
        Wt2[c * 128 + k] = f2bf(W2[i]);
    }
}

// ---------------- MFMA GEMM: G16[r][c] = bf16( (X[r]·W[:,c]) * dinv[r] ) ----------------
// K = 128. Block = 256 thr (4 waves), BM = 64 rows, full M cols.
// B-fragments read straight from global Wt (L1-resident: 32/16 KB, shared by all blocks).
// Only the streamed X tile goes through LDS (16 KB, XOR-swizzled).

template <int M, bool IN_BF16>
__global__ __launch_bounds__(256) void gemm_mfma(const void* __restrict__ Xv,
                                                 const unsigned short* __restrict__ Wt,
                                                 const float* __restrict__ dinv,
                                                 unsigned short* __restrict__ G16,
                                                 int n) {
    constexpr int K = 128;
    constexpr int BM = 64;
    __shared__ unsigned short Xs[BM * K];  // [m][k], byte addr ^ ((m&7)<<4)
    int t = threadIdx.x;
    int blockRow = blockIdx.x * BM;

    // ---- stage X tile (convert to bf16 if needed) ----
    if (!IN_BF16) {
        const float* X = (const float*)Xv;
#pragma unroll
        for (int i = 0; i < 8; ++i) {       // 64 rows * 32 float4
            int f = t + i * 256;
            int m = f >> 5, k4 = f & 31;
            float4 v = make_float4(0.f, 0.f, 0.f, 0.f);
            if (blockRow + m < n) v = ((const float4*)(X + (size_t)(blockRow + m) * K))[k4];
            uint2 p;
            p.x = (unsigned)f2bf(v.x) | ((unsigned)f2bf(v.y) << 16);
            p.y = (unsigned)f2bf(v.z) | ((unsigned)f2bf(v.w) << 16);
            int addr = (m * 256 + k4 * 8) ^ ((m & 7) << 4);
            *(uint2*)((char*)Xs + addr) = p;
        }
    } else {
        const unsigned short* X = (const unsigned short*)Xv;
#pragma unroll
        for (int i = 0; i < 4; ++i) {       // 64 rows * 16 uint4
            int f = t + i * 256;
            int m = f >> 4, k8 = f & 15;
            uint4 v = make_uint4(0u, 0u, 0u, 0u);
            if (blockRow + m < n) v = ((const uint4*)(X + (size_t)(blockRow + m) * K))[k8];
            int addr = (m * 256 + k8 * 16) ^ ((m & 7) << 4);
            *(uint4*)((char*)Xs + addr) = v;
        }
    }
    __syncthreads();

    int w = t >> 6, l = t & 63;
    int lg = l >> 4, lm = l & 15;
    constexpr int NCT = M / 16;

    union F8 { uint2 u2[2]; bf16x8 v; };

    // A frags for this wave's 16-row tile
    bf16x8 afr[4];
    int mrow = 16 * w + lm;
    int swa = (mrow & 7) << 4;
#pragma unroll
    for (int kk = 0; kk < 4; ++kk) {
        int pa = mrow * 256 + (32 * kk + 4 * lg) * 2;
        F8 a;
        a.u2[0] = *(const uint2*)((const char*)Xs + (pa ^ swa));
        a.u2[1] = *(const uint2*)((const char*)Xs + ((pa + 32) ^ swa));
        afr[kk] = a.v;
    }

    f32x4 acc[NCT];
#pragma unroll
    for (int ct = 0; ct < NCT; ++ct) acc[ct] = (f32x4){0.f, 0.f, 0.f, 0.f};

#pragma unroll
    for (int ct = 0; ct < NCT; ++ct) {
        const char* wp = (const char*)Wt + (ct * 16 + lm) * 256 + lg * 8;
#pragma unroll
        for (int kk = 0; kk < 4; ++kk) {
            F8 b;
            b.u2[0] = *(const uint2*)(wp + kk * 64);
            b.u2[1] = *(const uint2*)(wp + kk * 64 + 32);
            acc[ct] = __builtin_amdgcn_mfma_f32_16x16x32_bf16(afr[kk], b.v, acc[ct], 0, 0, 0);
        }
    }

    // ---- epilogue: scale by dinv, emit bf16 ----
    float dv[4];
#pragma unroll
    for (int q = 0; q < 4; ++q) {
        int r = blockRow + 16 * w + 4 * lg + q;
        dv[q] = (r < n) ? dinv[r] : 0.f;
    }
#pragma unroll
    for (int ct = 0; ct < NCT; ++ct) {
#pragma unroll
        for (int q = 0; q < 4; ++q) {
            int r = blockRow + 16 * w + 4 * lg + q;
            if (r < n) G16[(size_t)r * M + ct * 16 + lm] = f2bf(acc[ct][q] * dv[q]);
        }
    }
}

// ---------------- Aggregation (bf16 table, fp32 accumulate) ----------------

__global__ __launch_bounds__(256) void agg_d128(const unsigned short* __restrict__ G16,
                                                const int* __restrict__ srcs,
                                                const int* __restrict__ rowptr,
                                                const float* __restrict__ dinv,
                                                const float* __restrict__ bias,
                                                unsigned short* __restrict__ out, int n) {
    int wid = (blockIdx.x * blockDim.x + threadIdx.x) >> 6;
    int lane = threadIdx.x & 63;
    if (wid >= n) return;
    int g = lane >> 4;
    int lh = lane & 15;

    float acc[8];
    {
        uint4 u = make_uint4(0u, 0u, 0u, 0u);
        if (g == 0) u = ((const uint4*)(G16 + (size_t)wid * 128))[lh];
        acc[0] = bf_lo(u.x); acc[1] = bf_hi(u.x);
        acc[2] = bf_lo(u.y); acc[3] = bf_hi(u.y);
        acc[4] = bf_lo(u.z); acc[5] = bf_hi(u.z);
        acc[6] = bf_lo(u.w); acc[7] = bf_hi(u.w);
    }

    int beg = rowptr[wid], end = rowptr[wid + 1];
    for (int base = beg; base < end; base += 64) {
        int m = end - base;
        if (m > 64) m = 64;
        int sv = (base + lane < end) ? srcs[base + lane] : 0;
        for (int j = 0; j < m; j += 4) {
            int s = __shfl(sv, j + g);
            uint4 u = ((const uint4*)(G16 + (size_t)s * 128))[lh];
            if (j + g >= m) u = make_uint4(0u, 0u, 0u, 0u);
            acc[0] += bf_lo(u.x); acc[1] += bf_hi(u.x);
            acc[2] += bf_lo(u.y); acc[3] += bf_hi(u.y);
            acc[4] += bf_lo(u.z); acc[5] += bf_hi(u.z);
            acc[6] += bf_lo(u.w); acc[7] += bf_hi(u.w);
        }
    }

#pragma unroll
    for (int k = 0; k < 8; ++k) {
        acc[k] += __shfl_xor(acc[k], 16);
        acc[k] += __shfl_xor(acc[k], 32);
    }

    if (g < 2) {
        float di = dinv[wid];
        int idx = 2 * lh + g;
        float4 b = ((const float4*)bias)[idx];
        int k0 = 4 * g;
        float o0 = fmaxf(acc[k0 + 0] * di + b.x, 0.f);
        float o1 = fmaxf(acc[k0 + 1] * di + b.y, 0.f);
        float o2 = fmaxf(acc[k0 + 2] * di + b.z, 0.f);
        float o3 = fmaxf(acc[k0 + 3] * di + b.w, 0.f);
        uint2 p;
        p.x = (unsigned)f2bf(o0) | ((unsigned)f2bf(o1) << 16);
        p.y = (unsigned)f2bf(o2) | ((unsigned)f2bf(o3) << 16);
        ((uint2*)(out + (size_t)wid * 128))[idx] = p;
    }
}

__global__ __launch_bounds__(256) void agg_d64(const unsigned short* __restrict__ G16,
                                               const int* __restrict__ srcs,
                                               const int* __restrict__ rowptr,
                                               const float* __restrict__ dinv,
                                               const float* __restrict__ bias,
                                               float* __restrict__ out, int n) {
    int wid = (blockIdx.x * blockDim.x + threadIdx.x) >> 6;
    int lane = threadIdx.x & 63;
    if (wid >= n) return;
    int g = lane >> 3;
    int lh = lane & 7;

    float acc[8];
    {
        uint4 u = make_uint4(0u, 0u, 0u, 0u);
        if (g == 0) u = ((const uint4*)(G16 + (size_t)wid * 64))[lh];
        acc[0] = bf_lo(u.x); acc[1] = bf_hi(u.x);
        acc[2] = bf_lo(u.y); acc[3] = bf_hi(u.y);
        acc[4] = bf_lo(u.z); acc[5] = bf_hi(u.z);
        acc[6] = bf_lo(u.w); acc[7] = bf_hi(u.w);
    }

    int beg = rowptr[wid], end = rowptr[wid + 1];
    for (int base = beg; base < end; base += 64) {
        int m = end - base;
        if (m > 64) m = 64;
        int sv = (base + lane < end) ? srcs[base + lane] : 0;
        for (int j = 0; j < m; j += 8) {
            int s = __shfl(sv, j + g);
            uint4 u = ((const uint4*)(G16 + (size_t)s * 64))[lh];
            if (j + g >= m) u = make_uint4(0u, 0u, 0u, 0u);
            acc[0] += bf_lo(u.x); acc[1] += bf_hi(u.x);
            acc[2] += bf_lo(u.y); acc[3] += bf_hi(u.y);
            acc[4] += bf_lo(u.z); acc[5] += bf_hi(u.z);
            acc[6] += bf_lo(u.w); acc[7] += bf_hi(u.w);
        }
    }

#pragma unroll
    for (int k = 0; k < 8; ++k) {
        acc[k] += __shfl_xor(acc[k], 8);
        acc[k] += __shfl_xor(acc[k], 16);
        acc[k] += __shfl_xor(acc[k], 32);
    }

    if (g < 2) {
        float di = dinv[wid];
        int idx = 2 * lh + g;
        float4 b = ((const float4*)bias)[idx];
        int k0 = 4 * g;
        float4 o;
        o.x = acc[k0 + 0] * di + b.x;
        o.y = acc[k0 + 1] * di + b.y;
        o.z = acc[k0 + 2] * di + b.z;
        o.w = acc[k0 + 3] * di + b.w;
        ((float4*)(out + (size_t)wid * 64))[idx] = o;
    }
}

// ---------------- launch ----------------

extern "C" void kernel_launch(void* const* d_in, const int* in_sizes, int n_in,
                              void* d_out, int out_size, void* d_ws, size_t ws_size,
                              hipStream_t stream) {
    const float* x = (const float*)d_in[0];
    const int* ei = (const int*)d_in[1];
    const float* W1 = (const float*)d_in[2];
    const float* b1 = (const float*)d_in[3];
    const float* W2 = (const float*)d_in[4];
    const float* b2 = (const float*)d_in[5];
    float* out = (float*)d_out;

    const int n = in_sizes[0] / 128;  // 100000
    const int E = in_sizes[1] / 2;    // 1600000

    char* ws = (char*)d_ws;
    size_t off = 0;
    auto alloc = [&](size_t bytes) {
        void* p = ws + off;
        off = (off + bytes + 255) & ~(size_t)255;
        return p;
    };
    unsigned short* g1 = (unsigned short*)alloc((size_t)n * 128 * 2);  // bf16 gather table
    unsigned short* a1 = (unsigned short*)alloc((size_t)n * 128 * 2);  // bf16 relu(layer1)
    int* cnt = (int*)alloc((size_t)n * 4);
    int* rowptr = (int*)alloc(((size_t)n + 1) * 4);
    float* dinv = (float*)alloc((size_t)n * 4);
    int* srcs = (int*)alloc((size_t)E * 4);
    int* rank = (int*)alloc((size_t)E * 4);
    int* blocksum = (int*)alloc(1024 * 4);
    unsigned short* Wt1 = (unsigned short*)alloc(128 * 128 * 2);  // bf16 W1^T [c][k]
    unsigned short* Wt2 = (unsigned short*)alloc(64 * 128 * 2);   // bf16 W2^T [c][k]
    unsigned short* g2 = g1;  // reuse for layer 2

    const int nb_scan = (n + 1023) / 1024;
    int eb = (E + 255) / 256;
    int gb = (n + 63) / 64;  // MFMA gemm blocks (BM=64)

    hipMemsetAsync(cnt, 0, (size_t)n * 4, stream);

    prep_w<<<96, 256, 0, stream>>>(W1, W2, Wt1, Wt2);
    count_rank<<<eb, 256, 0, stream>>>(ei, E, cnt, rank, n);
    scan_partial<<<nb_scan, 256, 0, stream>>>(cnt, n, blocksum);
    scan_blocksums<<<1, 256, 0, stream>>>(blocksum, nb_scan);
    scan_final<<<nb_scan, 256, 0, stream>>>(cnt, blocksum, n, rowptr, dinv);
    fill_scatter<<<eb, 256, 0, stream>>>(ei, E, rowptr, rank, srcs, n);

    // layer 1
    gemm_mfma<128, false><<<gb, 256, 0, stream>>>(x, Wt1, dinv, g1, n);
    agg_d128<<<(n + 3) / 4, 256, 0, stream>>>(g1, srcs, rowptr, dinv, b1, a1, n);

    // layer 2
    gemm_mfma<64, true><<<gb, 256, 0, stream>>>(a1, Wt2, dinv, g2, n);
    agg_d64<<<(n + 3) / 4, 256, 0, stream>>>(g2, srcs, rowptr, dinv, b2, out, n);
}

// Round 9
// 262.739 us; speedup vs baseline: 2.8385x; 1.2173x over previous
//
#include <hip/hip_runtime.h>

typedef __attribute__((ext_vector_type(8))) short bf16x8;
typedef __attribute__((ext_vector_type(4))) float f32x4;

// ---------------- bf16 helpers (hand-rolled RNE) ----------------

__device__ __forceinline__ unsigned short f2bf(float f) {
    unsigned u = __float_as_uint(f);
    u += 0x7fffu + ((u >> 16) & 1u);
    return (unsigned short)(u >> 16);
}
__device__ __forceinline__ float bf_lo(unsigned u) { return __uint_as_float(u << 16); }
__device__ __forceinline__ float bf_hi(unsigned u) { return __uint_as_float(u & 0xffff0000u); }

// ---------------- CSR build ----------------

__global__ void count_rank(const int* __restrict__ ei, int E,
                           int* __restrict__ cnt, int* __restrict__ rank, int n) {
    int e = blockIdx.x * blockDim.x + threadIdx.x;
    if (e < E) {
        int d = ei[E + e];
        if ((unsigned)d < (unsigned)n) rank[e] = atomicAdd(&cnt[d], 1);
    }
}

__global__ __launch_bounds__(256) void scan_partial(const int* __restrict__ cnt,
                                                    int n, int* __restrict__ blocksum) {
    int base = blockIdx.x * 1024;
    int t = threadIdx.x;
    int s = 0;
#pragma unroll
    for (int j = 0; j < 4; ++j) {
        int i = base + (t << 2) + j;
        if (i < n) s += cnt[i];
    }
#pragma unroll
    for (int off = 1; off < 64; off <<= 1) s += __shfl_xor(s, off);
    __shared__ int ws[4];
    if ((t & 63) == 0) ws[t >> 6] = s;
    __syncthreads();
    if (t == 0) blocksum[blockIdx.x] = ws[0] + ws[1] + ws[2] + ws[3];
}

__global__ __launch_bounds__(256) void scan_blocksums(int* __restrict__ blocksum, int nb) {
    __shared__ int sh[256];
    int t = threadIdx.x;
    sh[t] = (t < nb) ? blocksum[t] : 0;
    __syncthreads();
#pragma unroll
    for (int off = 1; off < 256; off <<= 1) {
        int v = (t >= off) ? sh[t - off] : 0;
        __syncthreads();
        sh[t] += v;
        __syncthreads();
    }
    if (t < nb) blocksum[t] = (t == 0) ? 0 : sh[t - 1];
}

__global__ __launch_bounds__(256) void scan_final(const int* __restrict__ cnt,
                                                  const int* __restrict__ blockoff,
                                                  int n, int* __restrict__ rowptr,
                                                  float* __restrict__ dinv) {
    int base = blockIdx.x * 1024;
    int t = threadIdx.x;
    int v[4];
    int s = 0;
#pragma unroll
    for (int j = 0; j < 4; ++j) {
        int i = base + (t << 2) + j;
        v[j] = (i < n) ? cnt[i] : 0;
        s += v[j];
    }
    __shared__ int sh[256];
    sh[t] = s;
    __syncthreads();
#pragma unroll
    for (int off = 1; off < 256; off <<= 1) {
        int x = (t >= off) ? sh[t - off] : 0;
        __syncthreads();
        sh[t] += x;
        __syncthreads();
    }
    int run = blockoff[blockIdx.x] + (sh[t] - s);
#pragma unroll
    for (int j = 0; j < 4; ++j) {
        int i = base + (t << 2) + j;
        if (i < n) {
            rowptr[i] = run;
            dinv[i] = rsqrtf((float)(v[j] + 1));
            run += v[j];
        }
    }
    if (base + (t << 2) < n && n <= base + (t << 2) + 4) rowptr[n] = run;
}

__global__ void fill_scatter(const int* __restrict__ ei, int E,
                             const int* __restrict__ rowptr,
                             const int* __restrict__ rank,
                             int* __restrict__ srcs, int n) {
    int e = blockIdx.x * blockDim.x + threadIdx.x;
    if (e < E) {
        int s = ei[e];
        int d = ei[E + e];
        if ((unsigned)d < (unsigned)n && (unsigned)s < (unsigned)n)
            srcs[rowptr[d] + rank[e]] = s;
    }
}

// ---------------- one-time W -> bf16 transposed [c][k] ----------------

__global__ __launch_bounds__(256) void prep_w(const float* __restrict__ W1,
                                              const float* __restrict__ W2,
                                              unsigned short* __restrict__ Wt1,
                                              unsigned short* __restrict__ Wt2) {
    int t = blockIdx.x * blockDim.x + threadIdx.x;
    if (t < 128 * 128) {          // W1: [k][c] 128x128, coalesced read
        int k = t >> 7, c = t & 127;
        Wt1[c * 128 + k] = f2bf(W1[t]);
    } else if (t < 128 * 128 + 128 * 64) {  // W2: [k][c] 128x64
        int i = t - 128 * 128;
        int k = i >> 6, c = i & 63;
        Wt2[c * 128 + k] = f2bf(W2[i]);
    }
}

// ---------------- MFMA GEMM: G16[r][c] = bf16( (X[r]·W[:,c]) * dinv[r] ) ----------------
// K = 128, BM = 64, 4 waves. Wt staged to LDS ONCE per block (coalesced uint4),
// block grid-strides over row tiles to amortize it (kills the global hot-table
// L2 serialization seen in r6-r8: 3 different gemms all pinned at ~80us).
// Both LDS tiles XOR-swizzled (byte addr ^ ((row&7)<<4)) for conflict-free frag reads.

template <int M, bool IN_BF16>
__global__ __launch_bounds__(256) void gemm_mfma(const void* __restrict__ Xv,
                                                 const unsigned short* __restrict__ Wt,
                                                 const float* __restrict__ dinv,
                                                 unsigned short* __restrict__ G16,
                                                 int n, int ntiles) {
    constexpr int K = 128;
    constexpr int BM = 64;
    __shared__ unsigned short Xs[BM * K];    // 16 KB
    __shared__ unsigned short Wl[M * K];     // 32 KB (M=128) / 16 KB (M=64)
    int t = threadIdx.x;

    // ---- stage Wt -> LDS once (coalesced, swizzled) ----
#pragma unroll
    for (int i = 0; i < M / 16; ++i) {       // M*128 shorts = M*16 uint4
        int f = t + i * 256;
        int c = f >> 4, k8 = f & 15;
        uint4 v = ((const uint4*)Wt)[f];
        int addr = (c * 256 + k8 * 16) ^ ((c & 7) << 4);
        *(uint4*)((char*)Wl + addr) = v;
    }

    int w = t >> 6, l = t & 63;
    int lg = l >> 4, lm = l & 15;
    constexpr int NCT = M / 16;
    union F8 { uint2 u2[2]; bf16x8 v; };

    for (int tile = blockIdx.x; tile < ntiles; tile += gridDim.x) {
        int blockRow = tile * BM;
        __syncthreads();  // previous iter's Xs reads done (also orders first Wl use)

        // ---- stage X tile ----
        if (!IN_BF16) {
            const float* X = (const float*)Xv;
#pragma unroll
            for (int i = 0; i < 8; ++i) {    // 64 rows * 32 float4
                int f = t + i * 256;
                int m = f >> 5, k4 = f & 31;
                float4 v = make_float4(0.f, 0.f, 0.f, 0.f);
                if (blockRow + m < n) v = ((const float4*)(X + (size_t)(blockRow + m) * K))[k4];
                uint2 p;
                p.x = (unsigned)f2bf(v.x) | ((unsigned)f2bf(v.y) << 16);
                p.y = (unsigned)f2bf(v.z) | ((unsigned)f2bf(v.w) << 16);
                int addr = (m * 256 + k4 * 8) ^ ((m & 7) << 4);
                *(uint2*)((char*)Xs + addr) = p;
            }
        } else {
            const unsigned short* X = (const unsigned short*)Xv;
#pragma unroll
            for (int i = 0; i < 4; ++i) {    // 64 rows * 16 uint4
                int f = t + i * 256;
                int m = f >> 4, k8 = f & 15;
                uint4 v = make_uint4(0u, 0u, 0u, 0u);
                if (blockRow + m < n) v = ((const uint4*)(X + (size_t)(blockRow + m) * K))[k8];
                int addr = (m * 256 + k8 * 16) ^ ((m & 7) << 4);
                *(uint4*)((char*)Xs + addr) = v;
            }
        }
        __syncthreads();

        // ---- A frags ----
        bf16x8 afr[4];
        int mrow = 16 * w + lm;
        int swa = (mrow & 7) << 4;
#pragma unroll
        for (int kk = 0; kk < 4; ++kk) {
            int pa = mrow * 256 + (32 * kk + 4 * lg) * 2;
            F8 a;
            a.u2[0] = *(const uint2*)((const char*)Xs + (pa ^ swa));
            a.u2[1] = *(const uint2*)((const char*)Xs + ((pa + 32) ^ swa));
            afr[kk] = a.v;
        }

        f32x4 acc[NCT];
#pragma unroll
        for (int ct = 0; ct < NCT; ++ct) acc[ct] = (f32x4){0.f, 0.f, 0.f, 0.f};

#pragma unroll
        for (int ct = 0; ct < NCT; ++ct) {
            int c = ct * 16 + lm;
            int swc = (c & 7) << 4;
#pragma unroll
            for (int kk = 0; kk < 4; ++kk) {
                int pb = c * 256 + (32 * kk + 4 * lg) * 2;
                F8 b;
                b.u2[0] = *(const uint2*)((const char*)Wl + (pb ^ swc));
                b.u2[1] = *(const uint2*)((const char*)Wl + ((pb + 32) ^ swc));
                acc[ct] = __builtin_amdgcn_mfma_f32_16x16x32_bf16(afr[kk], b.v, acc[ct], 0, 0, 0);
            }
        }

        // ---- epilogue: scale by dinv, emit bf16 ----
        float dv[4];
#pragma unroll
        for (int q = 0; q < 4; ++q) {
            int r = blockRow + 16 * w + 4 * lg + q;
            dv[q] = (r < n) ? dinv[r] : 0.f;
        }
#pragma unroll
        for (int ct = 0; ct < NCT; ++ct) {
#pragma unroll
            for (int q = 0; q < 4; ++q) {
                int r = blockRow + 16 * w + 4 * lg + q;
                if (r < n) G16[(size_t)r * M + ct * 16 + lm] = f2bf(acc[ct][q] * dv[q]);
            }
        }
    }
}

// ---------------- Aggregation (bf16 table, fp32 accumulate) ----------------

__global__ __launch_bounds__(256) void agg_d128(const unsigned short* __restrict__ G16,
                                                const int* __restrict__ srcs,
                                                const int* __restrict__ rowptr,
                                                const float* __restrict__ dinv,
                                                const float* __restrict__ bias,
                                                unsigned short* __restrict__ out, int n) {
    int wid = (blockIdx.x * blockDim.x + threadIdx.x) >> 6;
    int lane = threadIdx.x & 63;
    if (wid >= n) return;
    int g = lane >> 4;
    int lh = lane & 15;

    float acc[8];
    {
        uint4 u = make_uint4(0u, 0u, 0u, 0u);
        if (g == 0) u = ((const uint4*)(G16 + (size_t)wid * 128))[lh];
        acc[0] = bf_lo(u.x); acc[1] = bf_hi(u.x);
        acc[2] = bf_lo(u.y); acc[3] = bf_hi(u.y);
        acc[4] = bf_lo(u.z); acc[5] = bf_hi(u.z);
        acc[6] = bf_lo(u.w); acc[7] = bf_hi(u.w);
    }

    int beg = rowptr[wid], end = rowptr[wid + 1];
    for (int base = beg; base < end; base += 64) {
        int m = end - base;
        if (m > 64) m = 64;
        int sv = (base + lane < end) ? srcs[base + lane] : 0;
        for (int j = 0; j < m; j += 4) {
            int s = __shfl(sv, j + g);
            uint4 u = ((const uint4*)(G16 + (size_t)s * 128))[lh];
            if (j + g >= m) u = make_uint4(0u, 0u, 0u, 0u);
            acc[0] += bf_lo(u.x); acc[1] += bf_hi(u.x);
            acc[2] += bf_lo(u.y); acc[3] += bf_hi(u.y);
            acc[4] += bf_lo(u.z); acc[5] += bf_hi(u.z);
            acc[6] += bf_lo(u.w); acc[7] += bf_hi(u.w);
        }
    }

#pragma unroll
    for (int k = 0; k < 8; ++k) {
        acc[k] += __shfl_xor(acc[k], 16);
        acc[k] += __shfl_xor(acc[k], 32);
    }

    if (g < 2) {
        float di = dinv[wid];
        int idx = 2 * lh + g;
        float4 b = ((const float4*)bias)[idx];
        int k0 = 4 * g;
        float o0 = fmaxf(acc[k0 + 0] * di + b.x, 0.f);
        float o1 = fmaxf(acc[k0 + 1] * di + b.y, 0.f);
        float o2 = fmaxf(acc[k0 + 2] * di + b.z, 0.f);
        float o3 = fmaxf(acc[k0 + 3] * di + b.w, 0.f);
        uint2 p;
        p.x = (unsigned)f2bf(o0) | ((unsigned)f2bf(o1) << 16);
        p.y = (unsigned)f2bf(o2) | ((unsigned)f2bf(o3) << 16);
        ((uint2*)(out + (size_t)wid * 128))[idx] = p;
    }
}

__global__ __launch_bounds__(256) void agg_d64(const unsigned short* __restrict__ G16,
                                               const int* __restrict__ srcs,
                                               const int* __restrict__ rowptr,
                                               const float* __restrict__ dinv,
                                               const float* __restrict__ bias,
                                               float* __restrict__ out, int n) {
    int wid = (blockIdx.x * blockDim.x + threadIdx.x) >> 6;
    int lane = threadIdx.x & 63;
    if (wid >= n) return;
    int g = lane >> 3;
    int lh = lane & 7;

    float acc[8];
    {
        uint4 u = make_uint4(0u, 0u, 0u, 0u);
        if (g == 0) u = ((const uint4*)(G16 + (size_t)wid * 64))[lh];
        acc[0] = bf_lo(u.x); acc[1] = bf_hi(u.x);
        acc[2] = bf_lo(u.y); acc[3] = bf_hi(u.y);
        acc[4] = bf_lo(u.z); acc[5] = bf_hi(u.z);
        acc[6] = bf_lo(u.w); acc[7] = bf_hi(u.w);
    }

    int beg = rowptr[wid], end = rowptr[wid + 1];
    for (int base = beg; base < end; base += 64) {
        int m = end - base;
        if (m > 64) m = 64;
        int sv = (base + lane < end) ? srcs[base + lane] : 0;
        for (int j = 0; j < m; j += 8) {
            int s = __shfl(sv, j + g);
            uint4 u = ((const uint4*)(G16 + (size_t)s * 64))[lh];
            if (j + g >= m) u = make_uint4(0u, 0u, 0u, 0u);
            acc[0] += bf_lo(u.x); acc[1] += bf_hi(u.x);
            acc[2] += bf_lo(u.y); acc[3] += bf_hi(u.y);
            acc[4] += bf_lo(u.z); acc[5] += bf_hi(u.z);
            acc[6] += bf_lo(u.w); acc[7] += bf_hi(u.w);
        }
    }

#pragma unroll
    for (int k = 0; k < 8; ++k) {
        acc[k] += __shfl_xor(acc[k], 8);
        acc[k] += __shfl_xor(acc[k], 16);
        acc[k] += __shfl_xor(acc[k], 32);
    }

    if (g < 2) {
        float di = dinv[wid];
        int idx = 2 * lh + g;
        float4 b = ((const float4*)bias)[idx];
        int k0 = 4 * g;
        float4 o;
        o.x = acc[k0 + 0] * di + b.x;
        o.y = acc[k0 + 1] * di + b.y;
        o.z = acc[k0 + 2] * di + b.z;
        o.w = acc[k0 + 3] * di + b.w;
        ((float4*)(out + (size_t)wid * 64))[idx] = o;
    }
}

// ---------------- launch ----------------

extern "C" void kernel_launch(void* const* d_in, const int* in_sizes, int n_in,
                              void* d_out, int out_size, void* d_ws, size_t ws_size,
                              hipStream_t stream) {
    const float* x = (const float*)d_in[0];
    const int* ei = (const int*)d_in[1];
    const float* W1 = (const float*)d_in[2];
    const float* b1 = (const float*)d_in[3];
    const float* W2 = (const float*)d_in[4];
    const float* b2 = (const float*)d_in[5];
    float* out = (float*)d_out;

    const int n = in_sizes[0] / 128;  // 100000
    const int E = in_sizes[1] / 2;    // 1600000

    char* ws = (char*)d_ws;
    size_t off = 0;
    auto alloc = [&](size_t bytes) {
        void* p = ws + off;
        off = (off + bytes + 255) & ~(size_t)255;
        return p;
    };
    unsigned short* g1 = (unsigned short*)alloc((size_t)n * 128 * 2);  // bf16 gather table
    unsigned short* a1 = (unsigned short*)alloc((size_t)n * 128 * 2);  // bf16 relu(layer1)
    int* cnt = (int*)alloc((size_t)n * 4);
    int* rowptr = (int*)alloc(((size_t)n + 1) * 4);
    float* dinv = (float*)alloc((size_t)n * 4);
    int* srcs = (int*)alloc((size_t)E * 4);
    int* rank = (int*)alloc((size_t)E * 4);
    int* blocksum = (int*)alloc(1024 * 4);
    unsigned short* Wt1 = (unsigned short*)alloc(128 * 128 * 2);  // bf16 W1^T [c][k]
    unsigned short* Wt2 = (unsigned short*)alloc(64 * 128 * 2);   // bf16 W2^T [c][k]
    unsigned short* g2 = g1;  // reuse for layer 2

    const int nb_scan = (n + 1023) / 1024;
    int eb = (E + 255) / 256;
    const int ntiles = (n + 63) / 64;  // 1563 row tiles (BM=64)
    const int gb = 768;                // 3 blocks/CU; each block does ~2 tiles

    hipMemsetAsync(cnt, 0, (size_t)n * 4, stream);

    prep_w<<<96, 256, 0, stream>>>(W1, W2, Wt1, Wt2);
    count_rank<<<eb, 256, 0, stream>>>(ei, E, cnt, rank, n);
    scan_partial<<<nb_scan, 256, 0, stream>>>(cnt, n, blocksum);
    scan_blocksums<<<1, 256, 0, stream>>>(blocksum, nb_scan);
    scan_final<<<nb_scan, 256, 0, stream>>>(cnt, blocksum, n, rowptr, dinv);
    fill_scatter<<<eb, 256, 0, stream>>>(ei, E, rowptr, rank, srcs, n);

    // layer 1
    gemm_mfma<128, false><<<gb, 256, 0, stream>>>(x, Wt1, dinv, g1, n, ntiles);
    agg_d128<<<(n + 3) / 4, 256, 0, stream>>>(g1, srcs, rowptr, dinv, b1, a1, n);

    // layer 2
    gemm_mfma<64, true><<<gb, 256, 0, stream>>>(a1, Wt2, dinv, g2, n, ntiles);
    agg_d64<<<(n + 3) / 4, 256, 0, stream>>>(g2, srcs, rowptr, dinv, b2, out, n);
}